// Round 7
// baseline (1642.960 us; speedup 1.0000x reference)
//
#include <hip/hip_runtime.h>
#include <hip/hip_bf16.h>

// problem sizes
constexpr int Bz = 2, IMG = 512, Pp = 16, D = 384, E = 768, S = 16, L = 12;
constexpr int G = IMG / Pp;          // 32
constexpr int Np = G * G;            // 1024 patches
constexpr int M = Bz * Np;           // 2048 rows
constexpr int TWO_E = 2 * E;         // 1536

typedef short bf16x8 __attribute__((ext_vector_type(8)));
typedef float fx4    __attribute__((ext_vector_type(4)));

static __device__ __forceinline__ unsigned short f2bf(float f){
  unsigned int u = __float_as_uint(f);
  u = (u + 0x7FFFu + ((u >> 16) & 1u)) >> 16;       // RN-even
  return (unsigned short)u;
}
static __device__ __forceinline__ float bf2f(unsigned short h){
  return __uint_as_float(((unsigned int)h) << 16);
}

// fast 2^x / log2(x) via hardware transcendentals
static __device__ __forceinline__ float fexp2(float x){
  float r;
  asm("v_exp_f32 %0, %1" : "=v"(r) : "v"(x));
  return r;
}
static __device__ __forceinline__ float flog2(float x){
  float r;
  asm("v_log_f32 %0, %1" : "=v"(r) : "v"(x));
  return r;
}

// quad (4-lane) butterfly sum via DPP quad_perm
static __device__ __forceinline__ float quad_sum(float v){
  int a = __builtin_amdgcn_update_dpp(0, __float_as_int(v), 0xB1, 0xF, 0xF, true); // perm(1,0,3,2)
  v += __int_as_float(a);
  int b = __builtin_amdgcn_update_dpp(0, __float_as_int(v), 0x4E, 0xF, 0xF, true); // perm(2,3,0,1)
  v += __int_as_float(b);
  return v;
}

// ---------------- converted-weight store (device globals) ----------------
constexpr size_t PW_N = (size_t)D * 768;
constexpr size_t IW_N = (size_t)L * TWO_E * D;
constexpr size_t OW_N = (size_t)L * D * E;
constexpr size_t SW_N = (size_t)3 * D * D;
__device__ short g_pw_h[PW_N], g_pw_l[PW_N];
__device__ short g_iw_h[IW_N], g_iw_l[IW_N];
__device__ short g_ow_h[OW_N], g_ow_l[OW_N];
__device__ short g_swx_h[SW_N], g_swx_l[SW_N];

__global__ void convw_kernel(const float* __restrict__ pw, const float* __restrict__ iw,
                             const float* __restrict__ ow, const float* __restrict__ sw){
  size_t i = (size_t)blockIdx.x * 256 + threadIdx.x;
  if (i >= PW_N + IW_N + OW_N + SW_N) return;
  const float* src; short *dh, *dl; size_t j = i;
  if (j < PW_N){ src = pw; dh = g_pw_h; dl = g_pw_l; }
  else if ((j -= PW_N) < IW_N){ src = iw; dh = g_iw_h; dl = g_iw_l; }
  else if ((j -= IW_N) < OW_N){ src = ow; dh = g_ow_h; dl = g_ow_l; }
  else { j -= OW_N; src = sw; dh = g_swx_h; dl = g_swx_l; }
  float f = src[j];
  unsigned short h = f2bf(f);
  dh[j] = (short)h; dl[j] = (short)f2bf(f - bf2f(h));
}

// ---------------- patchify: pixels(f32) -> hi/lo bf16 (M x 768) ----------------
__global__ void patchify_kernel(const float* __restrict__ px,
                                short* __restrict__ oh, short* __restrict__ ol){
  int idx = blockIdx.x * 256 + threadIdx.x;
  if (idx >= M * 768) return;
  int k = idx % 768, m = idx / 768;
  int b = m / Np, n = m % Np;
  int gy = n / G, gx = n % G;
  int c = k / (Pp * Pp), r = k % (Pp * Pp);
  int py = r / Pp, pxi = r % Pp;
  size_t src = ((size_t)(b * 3 + c) * IMG + gy * Pp + py) * IMG + gx * Pp + pxi;
  float f = px[src];
  unsigned short h = f2bf(f);
  oh[idx] = (short)h; ol[idx] = (short)f2bf(f - bf2f(h));
}

// ---------------- final layernorm: f32 -> f32 ----------------
__global__ __launch_bounds__(256)
void layernorm_f32(const float* __restrict__ x, const float* __restrict__ w,
                   const float* __restrict__ bb, float* __restrict__ outf){
  int wave = threadIdx.x >> 6, lane = threadIdx.x & 63;
  int row = blockIdx.x * 4 + wave;
  const float* xr = x + (size_t)row * D;
  float v[6], s = 0.f, sq = 0.f;
  #pragma unroll
  for (int i = 0; i < 6; i++){ v[i] = xr[lane + 64 * i]; s += v[i]; sq += v[i] * v[i]; }
  #pragma unroll
  for (int off = 32; off; off >>= 1){ s += __shfl_xor(s, off); sq += __shfl_xor(sq, off); }
  float mean = s * (1.f / D);
  float var  = sq * (1.f / D) - mean * mean;
  float inv  = 1.0f / sqrtf(var + 1e-5f);
  #pragma unroll
  for (int i = 0; i < 6; i++){
    int c = lane + 64 * i;
    outf[(size_t)row * D + c] = (v[i] - mean) * inv * w[c] + bb[c];
  }
}

// ---------------- in-proj MFMA GEMM with FUSED LAYERNORM in A-staging ----------------
// Reads f32 x + per-row (sum,sumsq) stats (accumulated by producer epilogue), applies
// (x-mean)*inv*w+b and hi/lo bf16 split during staging. Replaces the layernorm_bf pass.
__global__ __launch_bounds__(256)
void gemm_in(const float* __restrict__ X, const float* __restrict__ rs,
             const float* __restrict__ nw, const float* __restrict__ nb,
             size_t woff, const float* __restrict__ bias,
             float* __restrict__ C, float* __restrict__ C2){
  constexpr int BKp = 40;
  __shared__ __align__(16) short sAh[64 * BKp],  sAl[64 * BKp];
  __shared__ __align__(16) short sWh[128 * BKp], sWl[128 * BKp];
  const short* Wh = g_iw_h + woff;
  const short* Wl = g_iw_l + woff;
  const int t = threadIdx.x, wid = t >> 6, lane = t & 63;
  const int m0 = blockIdx.y * 64, n0 = blockIdx.x * 128;
  const int wn = wid * 32;

  fx4 acc[4][2];
  #pragma unroll
  for (int a = 0; a < 4; a++)
    #pragma unroll
    for (int b = 0; b < 2; b++)
      #pragma unroll
      for (int i = 0; i < 4; i++) acc[a][b][i] = 0.f;

  const int rA = t >> 2, kpA = (t & 3) << 3;
  const int rW = t >> 1, kpW = (t & 1) << 4;
  const int row = lane & 15, kq = lane >> 4;

  // per-row LN stats (row fixed per thread for the whole k-loop)
  float mean, inv;
  {
    float s  = rs[(m0 + rA) * 2];
    float sq = rs[(m0 + rA) * 2 + 1];
    mean = s * (1.f / D);
    float var = sq * (1.f / D) - mean * mean;
    inv = 1.0f / sqrtf(var + 1e-5f);
  }

  for (int kt = 0; kt < D; kt += 32){
    { // fused LN staging: load f32 x, normalize, split hi/lo
      const float* xp = X + (size_t)(m0 + rA) * D + kt + kpA;
      float4 f0 = *(const float4*)xp, f1 = *(const float4*)(xp + 4);
      float4 wv0 = *(const float4*)(nw + kt + kpA), wv1 = *(const float4*)(nw + kt + kpA + 4);
      float4 bv0 = *(const float4*)(nb + kt + kpA), bv1 = *(const float4*)(nb + kt + kpA + 4);
      float f[8]  = {f0.x, f0.y, f0.z, f0.w, f1.x, f1.y, f1.z, f1.w};
      float wv[8] = {wv0.x, wv0.y, wv0.z, wv0.w, wv1.x, wv1.y, wv1.z, wv1.w};
      float bv[8] = {bv0.x, bv0.y, bv0.z, bv0.w, bv1.x, bv1.y, bv1.z, bv1.w};
      short hh[8], ll[8];
      #pragma unroll
      for (int i2 = 0; i2 < 8; i2++){
        float o = (f[i2] - mean) * inv * wv[i2] + bv[i2];
        unsigned short h = f2bf(o);
        hh[i2] = (short)h; ll[i2] = (short)f2bf(o - bf2f(h));
      }
      *(bf16x8*)&sAh[rA * BKp + kpA] = *(bf16x8*)hh;
      *(bf16x8*)&sAl[rA * BKp + kpA] = *(bf16x8*)ll;
    }
    *(bf16x8*)&sWh[rW * BKp + kpW]     = *(const bf16x8*)(Wh + (size_t)(n0 + rW) * D + kt + kpW);
    *(bf16x8*)&sWh[rW * BKp + kpW + 8] = *(const bf16x8*)(Wh + (size_t)(n0 + rW) * D + kt + kpW + 8);
    *(bf16x8*)&sWl[rW * BKp + kpW]     = *(const bf16x8*)(Wl + (size_t)(n0 + rW) * D + kt + kpW);
    *(bf16x8*)&sWl[rW * BKp + kpW + 8] = *(const bf16x8*)(Wl + (size_t)(n0 + rW) * D + kt + kpW + 8);
    __syncthreads();
    bf16x8 ah[4], al[4], bh[2], bl[2];
    #pragma unroll
    for (int tm = 0; tm < 4; tm++){
      ah[tm] = *(const bf16x8*)&sAh[(tm * 16 + row) * BKp + kq * 8];
      al[tm] = *(const bf16x8*)&sAl[(tm * 16 + row) * BKp + kq * 8];
    }
    #pragma unroll
    for (int tn = 0; tn < 2; tn++){
      bh[tn] = *(const bf16x8*)&sWh[(wn + tn * 16 + row) * BKp + kq * 8];
      bl[tn] = *(const bf16x8*)&sWl[(wn + tn * 16 + row) * BKp + kq * 8];
    }
    #pragma unroll
    for (int tm = 0; tm < 4; tm++)
      #pragma unroll
      for (int tn = 0; tn < 2; tn++){
        acc[tm][tn] = __builtin_amdgcn_mfma_f32_16x16x32_bf16(ah[tm], bh[tn], acc[tm][tn], 0, 0, 0);
        acc[tm][tn] = __builtin_amdgcn_mfma_f32_16x16x32_bf16(ah[tm], bl[tn], acc[tm][tn], 0, 0, 0);
        acc[tm][tn] = __builtin_amdgcn_mfma_f32_16x16x32_bf16(al[tm], bh[tn], acc[tm][tn], 0, 0, 0);
      }
    __syncthreads();
  }

  const int row4 = (lane >> 4) * 4, coln = lane & 15;
  #pragma unroll
  for (int tm = 0; tm < 4; tm++)
    #pragma unroll
    for (int tn = 0; tn < 2; tn++){
      int n = n0 + wn + tn * 16 + coln;
      int mb = m0 + tm * 16 + row4;
      float4 v4;
      float* vp = (float*)&v4;
      #pragma unroll
      for (int i = 0; i < 4; i++) vp[i] = acc[tm][tn][i] + bias[n];
      if (n < E){
        *(float4*)&C[(size_t)n * M + mb] = v4;          // xmT transposed
      } else {
        #pragma unroll
        for (int i = 0; i < 4; i++){
          float sig = 1.f / (1.f + expf(-vp[i]));
          vp[i] = vp[i] * sig;
        }
        *(float4*)&C2[(size_t)(n - E) * M + mb] = v4;   // zst transposed
      }
    }
}

// ---------------- patch MFMA GEMM 64x64 (pre-split A, +pos epilogue, +LN-stats accum) ----------------
__global__ __launch_bounds__(256)
void gemm_patch(const short* __restrict__ Ah, const short* __restrict__ Al,
                const float* __restrict__ bias, float* __restrict__ C,
                const float* __restrict__ pos, float* __restrict__ rsn){
  constexpr int BKp = 40;
  __shared__ __align__(16) short sAh[64 * BKp], sAl[64 * BKp];
  __shared__ __align__(16) short sWh[64 * BKp], sWl[64 * BKp];
  const int t = threadIdx.x, wid = t >> 6, lane = t & 63;
  const int m0 = blockIdx.y * 64, n0 = blockIdx.x * 64;

  fx4 acc[4];
  #pragma unroll
  for (int a = 0; a < 4; a++)
    #pragma unroll
    for (int i = 0; i < 4; i++) acc[a][i] = 0.f;

  const int r = t >> 2, kp = (t & 3) << 3;
  const int row = lane & 15, kq = lane >> 4;

  for (int kt = 0; kt < 768; kt += 32){
    *(bf16x8*)&sAh[r * BKp + kp] = *(const bf16x8*)(Ah + (size_t)(m0 + r) * 768 + kt + kp);
    *(bf16x8*)&sAl[r * BKp + kp] = *(const bf16x8*)(Al + (size_t)(m0 + r) * 768 + kt + kp);
    *(bf16x8*)&sWh[r * BKp + kp] = *(const bf16x8*)(g_pw_h + (size_t)(n0 + r) * 768 + kt + kp);
    *(bf16x8*)&sWl[r * BKp + kp] = *(const bf16x8*)(g_pw_l + (size_t)(n0 + r) * 768 + kt + kp);
    __syncthreads();
    bf16x8 bh = *(const bf16x8*)&sWh[(wid * 16 + row) * BKp + kq * 8];
    bf16x8 bl = *(const bf16x8*)&sWl[(wid * 16 + row) * BKp + kq * 8];
    #pragma unroll
    for (int tm = 0; tm < 4; tm++){
      bf16x8 ah = *(const bf16x8*)&sAh[(tm * 16 + row) * BKp + kq * 8];
      bf16x8 al = *(const bf16x8*)&sAl[(tm * 16 + row) * BKp + kq * 8];
      acc[tm] = __builtin_amdgcn_mfma_f32_16x16x32_bf16(ah, bh, acc[tm], 0, 0, 0);
      acc[tm] = __builtin_amdgcn_mfma_f32_16x16x32_bf16(ah, bl, acc[tm], 0, 0, 0);
      acc[tm] = __builtin_amdgcn_mfma_f32_16x16x32_bf16(al, bh, acc[tm], 0, 0, 0);
    }
    __syncthreads();
  }

  const int row4 = (lane >> 4) * 4, coln = lane & 15;
  #pragma unroll
  for (int tm = 0; tm < 4; tm++){
    int n = n0 + wid * 16 + coln;
    int mb = m0 + tm * 16 + row4;
    #pragma unroll
    for (int i = 0; i < 4; i++){
      int m = mb + i;
      float v = acc[tm][i] + bias[n] + pos[(size_t)(m & (Np - 1)) * D + n];
      C[(size_t)m * D + n] = v;
      // LN-stats accumulation for layer 0 (16-lane row-slice reduce + atomic)
      float s = v, sq = v * v;
      #pragma unroll
      for (int off = 1; off < 16; off <<= 1){ s += __shfl_xor(s, off); sq += __shfl_xor(sq, off); }
      if ((lane & 15) == 0){
        atomicAdd(&rsn[m * 2], s);
        atomicAdd(&rsn[m * 2 + 1], sq);
      }
    }
  }
}

// ---------------- scale MFMA GEMM 64x64: A = f32 x, hi/lo converted in staging ----------------
__global__ __launch_bounds__(256)
void gemm_scale(const float* __restrict__ A, size_t woff,
                const float* __restrict__ bias, float* __restrict__ C){
  constexpr int BKp = 40;
  __shared__ __align__(16) short sAh[64 * BKp], sAl[64 * BKp];
  __shared__ __align__(16) short sWh[64 * BKp], sWl[64 * BKp];
  const short* Wh = g_swx_h + woff;
  const short* Wl = g_swx_l + woff;
  const int t = threadIdx.x, wid = t >> 6, lane = t & 63;
  const int m0 = blockIdx.y * 64, n0 = blockIdx.x * 64;

  fx4 acc[4];
  #pragma unroll
  for (int a = 0; a < 4; a++)
    #pragma unroll
    for (int i = 0; i < 4; i++) acc[a][i] = 0.f;

  const int r = t >> 2, kp = (t & 3) << 3;
  const int row = lane & 15, kq = lane >> 4;

  for (int kt = 0; kt < D; kt += 32){
    {
      const float* ap = A + (size_t)(m0 + r) * D + kt + kp;
      float4 f0 = *(const float4*)ap, f1 = *(const float4*)(ap + 4);
      float f[8] = {f0.x, f0.y, f0.z, f0.w, f1.x, f1.y, f1.z, f1.w};
      short hh[8], ll[8];
      #pragma unroll
      for (int i = 0; i < 8; i++){
        unsigned short h = f2bf(f[i]);
        hh[i] = (short)h; ll[i] = (short)f2bf(f[i] - bf2f(h));
      }
      *(bf16x8*)&sAh[r * BKp + kp] = *(bf16x8*)hh;
      *(bf16x8*)&sAl[r * BKp + kp] = *(bf16x8*)ll;
    }
    *(bf16x8*)&sWh[r * BKp + kp] = *(const bf16x8*)(Wh + (size_t)(n0 + r) * D + kt + kp);
    *(bf16x8*)&sWl[r * BKp + kp] = *(const bf16x8*)(Wl + (size_t)(n0 + r) * D + kt + kp);
    __syncthreads();
    bf16x8 bh = *(const bf16x8*)&sWh[(wid * 16 + row) * BKp + kq * 8];
    bf16x8 bl = *(const bf16x8*)&sWl[(wid * 16 + row) * BKp + kq * 8];
    #pragma unroll
    for (int tm = 0; tm < 4; tm++){
      bf16x8 ah = *(const bf16x8*)&sAh[(tm * 16 + row) * BKp + kq * 8];
      bf16x8 al = *(const bf16x8*)&sAl[(tm * 16 + row) * BKp + kq * 8];
      acc[tm] = __builtin_amdgcn_mfma_f32_16x16x32_bf16(ah, bh, acc[tm], 0, 0, 0);
      acc[tm] = __builtin_amdgcn_mfma_f32_16x16x32_bf16(ah, bl, acc[tm], 0, 0, 0);
      acc[tm] = __builtin_amdgcn_mfma_f32_16x16x32_bf16(al, bh, acc[tm], 0, 0, 0);
    }
    __syncthreads();
  }

  const int row4 = (lane >> 4) * 4, coln = lane & 15;
  #pragma unroll
  for (int tm = 0; tm < 4; tm++){
    int n = n0 + wid * 16 + coln;
    int mb = m0 + tm * 16 + row4;
    #pragma unroll
    for (int i = 0; i < 4; i++){
      int m = mb + i;
      C[(size_t)m * D + n] = acc[tm][i] + bias[n];
    }
  }
}

// ---------------- out-proj MFMA GEMM, TRANSPOSED A; epilogue: residual + zero xBC + LN stats ----------------
__global__ __launch_bounds__(256)
void gemm_bf_at(const short* __restrict__ ATh, const short* __restrict__ ATl, int K,
                size_t woff, const float* __restrict__ bias,
                float* __restrict__ C, int ncols, float* __restrict__ zbuf,
                float* __restrict__ rsn){
  constexpr int BKp = 40;
  __shared__ __align__(16) short sAh[64 * BKp], sAl[64 * BKp];
  __shared__ __align__(16) short sWh[64 * BKp], sWl[64 * BKp];
  const short* Wh = g_ow_h + woff;
  const short* Wl = g_ow_l + woff;
  const int t = threadIdx.x, wid = t >> 6, lane = t & 63;
  const int m0 = blockIdx.y * 64, n0 = blockIdx.x * 64;

  fx4 acc[4];
  #pragma unroll
  for (int a = 0; a < 4; a++)
    #pragma unroll
    for (int i = 0; i < 4; i++) acc[a][i] = 0.f;

  const int rw = t >> 2, kpw = (t & 3) << 3;
  const int kr2 = (t & 15) * 2, mc4 = (t >> 4) * 4;
  const int row = lane & 15, kq = lane >> 4;

  for (int kt = 0; kt < K; kt += 32){
    {
      const uint2 h0 = *(const uint2*)(ATh + (size_t)(kt + kr2) * M + m0 + mc4);
      const uint2 h1 = *(const uint2*)(ATh + (size_t)(kt + kr2 + 1) * M + m0 + mc4);
      const uint2 l0 = *(const uint2*)(ATl + (size_t)(kt + kr2) * M + m0 + mc4);
      const uint2 l1 = *(const uint2*)(ATl + (size_t)(kt + kr2 + 1) * M + m0 + mc4);
      const unsigned int h0a[2] = {h0.x, h0.y}, h1a[2] = {h1.x, h1.y};
      const unsigned int l0a[2] = {l0.x, l0.y}, l1a[2] = {l1.x, l1.y};
      #pragma unroll
      for (int j = 0; j < 4; j++){
        unsigned int s0 = (h0a[j >> 1] >> ((j & 1) * 16)) & 0xFFFFu;
        unsigned int s1 = (h1a[j >> 1] >> ((j & 1) * 16)) & 0xFFFFu;
        *(unsigned int*)&sAh[(mc4 + j) * BKp + kr2] = s0 | (s1 << 16);
        unsigned int t0 = (l0a[j >> 1] >> ((j & 1) * 16)) & 0xFFFFu;
        unsigned int t1 = (l1a[j >> 1] >> ((j & 1) * 16)) & 0xFFFFu;
        *(unsigned int*)&sAl[(mc4 + j) * BKp + kr2] = t0 | (t1 << 16);
      }
    }
    *(bf16x8*)&sWh[rw * BKp + kpw] = *(const bf16x8*)(Wh + (size_t)(n0 + rw) * K + kt + kpw);
    *(bf16x8*)&sWl[rw * BKp + kpw] = *(const bf16x8*)(Wl + (size_t)(n0 + rw) * K + kt + kpw);
    __syncthreads();
    bf16x8 bh = *(const bf16x8*)&sWh[(wid * 16 + row) * BKp + kq * 8];
    bf16x8 bl = *(const bf16x8*)&sWl[(wid * 16 + row) * BKp + kq * 8];
    #pragma unroll
    for (int tm = 0; tm < 4; tm++){
      bf16x8 ah = *(const bf16x8*)&sAh[(tm * 16 + row) * BKp + kq * 8];
      bf16x8 al = *(const bf16x8*)&sAl[(tm * 16 + row) * BKp + kq * 8];
      acc[tm] = __builtin_amdgcn_mfma_f32_16x16x32_bf16(ah, bh, acc[tm], 0, 0, 0);
      acc[tm] = __builtin_amdgcn_mfma_f32_16x16x32_bf16(ah, bl, acc[tm], 0, 0, 0);
      acc[tm] = __builtin_amdgcn_mfma_f32_16x16x32_bf16(al, bh, acc[tm], 0, 0, 0);
    }
    __syncthreads();
  }

  const int row4 = (lane >> 4) * 4, coln = lane & 15;
  #pragma unroll
  for (int tm = 0; tm < 4; tm++)
    #pragma unroll
    for (int i = 0; i < 4; i++){
      int m = m0 + tm * 16 + row4 + i;
      int n = n0 + wid * 16 + coln;
      float v = acc[tm][i] + bias[n] + C[(size_t)m * ncols + n];
      C[(size_t)m * ncols + n] = v;
      // LN-stats accumulation for next layer (16-lane row-slice reduce + atomic)
      float s = v, sq = v * v;
      #pragma unroll
      for (int off = 1; off < 16; off <<= 1){ s += __shfl_xor(s, off); sq += __shfl_xor(sq, off); }
      if ((lane & 15) == 0){
        atomicAdd(&rsn[m * 2], s);
        atomicAdd(&rsn[m * 2 + 1], sq);
      }
    }

  // zero xBC for next layer's xp accumulation (stream order guarantees visibility)
  int gid = blockIdx.y * gridDim.x + blockIdx.x;
  int idx = gid * 256 + t;
  if (idx < M * 16)
    *(float2*)&zbuf[idx * 2] = make_float2(0.f, 0.f);
}

// ---------------- xp GEMM with FUSED depthwise conv+SiLU in A-staging ----------------
// (K-split x4, atomic): xBC [m][xB(16)|xC(16)]. Staging thread owns channel e=kt+ty and
// 4 consecutive m (tx*4); loads [m-4..m-1],[m..m+3] from xmT, computes causal 4-tap conv
// + SiLU in registers, writes both LDS As (GEMM input) and xcT (for scan). Each (e,m)
// covered exactly once across the grid -> conv_silu_t kernel deleted.
__global__ __launch_bounds__(256)
void gemm_xp(const float* __restrict__ xmT, const float* __restrict__ cw,
             const float* __restrict__ cb, const float* __restrict__ W,
             const float* __restrict__ bias, float* __restrict__ xcT,
             float* __restrict__ C){
  __shared__ float As[16][68];
  __shared__ float Ws[16][32 + 1];
  int tid = threadIdx.x;
  int tx = tid & 15, ty = tid >> 4;
  int m0 = blockIdx.y * 64, kb = blockIdx.x * 192;
  float acc[4][2];
  #pragma unroll
  for (int i = 0; i < 4; i++){ acc[i][0] = 0.f; acc[i][1] = 0.f; }
  for (int kt = kb; kt < kb + 192; kt += 16){
    { // fused conv staging: channel e = kt+ty, cols m = m0 + tx*4 + j
      int e = kt + ty;
      int mbase = m0 + tx * 4;
      const float* src = xmT + (size_t)e * M + mbase;
      float4 cur = *(const float4*)src;
      float4 prv = make_float4(0.f, 0.f, 0.f, 0.f);
      if (mbase >= 4) prv = *(const float4*)(src - 4);
      float4 w4 = *(const float4*)(cw + e * 4);
      float cb_e = cb[e];
      float vin[8] = {prv.x, prv.y, prv.z, prv.w, cur.x, cur.y, cur.z, cur.w};
      float4 outv;
      float* op = (float*)&outv;
      #pragma unroll
      for (int j = 0; j < 4; j++){
        int m = mbase + j, n = m & (Np - 1);
        float a = cb_e + w4.w * vin[4 + j];
        if (n >= 1) a += w4.z * vin[3 + j];
        if (n >= 2) a += w4.y * vin[2 + j];
        if (n >= 3) a += w4.x * vin[1 + j];
        float sig = 1.f / (1.f + expf(-a));
        op[j] = a * sig;
      }
      *(float4*)&As[ty][tx * 4] = outv;
      *(float4*)&xcT[(size_t)e * M + mbase] = outv;
    }
    if (tid < 128){
      int c = tid >> 2, kk = (tid & 3) << 2;
      const float* wp = W + (size_t)c * E + kt + kk;
      Ws[kk + 0][c] = wp[0]; Ws[kk + 1][c] = wp[1];
      Ws[kk + 2][c] = wp[2]; Ws[kk + 3][c] = wp[3];
    }
    __syncthreads();
    #pragma unroll
    for (int k = 0; k < 16; k++){
      float a[4], w[2];
      #pragma unroll
      for (int i = 0; i < 4; i++) a[i] = As[k][ty * 4 + i];
      w[0] = Ws[k][tx * 2]; w[1] = Ws[k][tx * 2 + 1];
      #pragma unroll
      for (int i = 0; i < 4; i++){ acc[i][0] += a[i] * w[0]; acc[i][1] += a[i] * w[1]; }
    }
    __syncthreads();
  }
  #pragma unroll
  for (int i = 0; i < 4; i++){
    int m = m0 + ty * 4 + i;
    #pragma unroll
    for (int j = 0; j < 2; j++){
      int n = tx * 2 + j;
      float v = acc[i][j];
      if (blockIdx.x == 0) v += bias[n];
      atomicAdd(&C[(size_t)m * 32 + n], v);
    }
  }
}

// ---------------- quad-per-chunk selective scan, register-prefetch pipelined (R3-best) ----------------
// 64 chunks of 16 positions; each chunk owned by a 4-lane quad, each lane holds 4 s-values
// in registers. Phase A: chunk-local h + sum(dt), 8-deep xb register FIFO. Phase B: 64-step
// serial combine on 16 lanes (LDS-based: keeps VGPR ~20-32; register-monoid variants in
// R4/R5 pushed VGPR >64 and lost 2x occupancy — do not revisit). Phase C: exact chain
// seeded with Hin, 6-deep dual-stream FIFO, 4-FMA dot + quad DPP reduce.
// Also zeroes the next-layer LN-stats buffer (safe: its last reader precedes this in stream).
// dt in [1e-4,1], A in [-16,-1] => dt*a in [-16,-1e-4]; ref's [-20,0] clip can't fire.
__global__ __launch_bounds__(256)
void scan_kernel(const float* __restrict__ xcT, const float* __restrict__ zst,
                 const float* __restrict__ xBC,
                 const float* __restrict__ Aptr, const float* __restrict__ Dp,
                 const float* __restrict__ dt_w, const float* __restrict__ dt_b,
                 short* __restrict__ yh, short* __restrict__ yl,
                 float* __restrict__ rsz){
  __shared__ float sdx[2176];       // {dt,xcv} pairs, swizzled: word = 2*pos + 2*(pos>>4)
  __shared__ float sHin[64 * 16];   // Hin[c][s]
  __shared__ float scr[2048];       // phase A/B: hloc[0..1023] + prodA[1024..2047]; phase C alias: yloc
  const int t = threadIdx.x;
  const int c = t >> 2;             // chunk 0..63
  const int u = t & 3;              // lane-in-quad
  const int r = blockIdx.x, b = r / E, e = r % E;
  const int bNp = b * Np;
  const float dpe = Dp[e];

  { // zero next-layer LN-stats buffer (M*2 floats)
    int gi = r * 256 + t;
    if (gi < M * 2) rsz[gi] = 0.f;
  }

  constexpr float LOG2E  = 1.4426950408889634f;
  constexpr float RLOG2E = 0.6931471805599453f;
  float4 a4 = *(const float4*)(Aptr + e * S + u * 4);
  const float a20 = a4.x * LOG2E, a21 = a4.y * LOG2E, a22 = a4.z * LOG2E, a23 = a4.w * LOG2E;
  const float* xcp = xcT + (size_t)e * M + bNp;
  const float* zsp = zst + (size_t)e * M + bNp;

  { // preload: dt[pos] = clip(softplus(xB . dt_w[e] + dt_b[e])), stage {dt,xc} swizzled.
    const float* dw = dt_w + e * 16;
    float4 w0 = *(const float4*)dw,       w1 = *(const float4*)(dw + 4);
    float4 w2 = *(const float4*)(dw + 8), w3 = *(const float4*)(dw + 12);
    float db = dt_b[e];
    float xcl[4];
    #pragma unroll
    for (int p = 0; p < 4; p++) xcl[p] = xcp[t + p * 256];
    float4 ra[2][4];
    {
      const float* xb0 = xBC + (size_t)(bNp + t) * 32;
      #pragma unroll
      for (int j = 0; j < 4; j++) ra[0][j] = *(const float4*)(xb0 + j * 4);
    }
    #pragma unroll
    for (int p = 0; p < 4; p++){
      int q = t + p * 256;
      float4 a0 = ra[p & 1][0], a1 = ra[p & 1][1], a2 = ra[p & 1][2], a3 = ra[p & 1][3];
      if (p < 3){
        const float* xbn = xBC + (size_t)(bNp + q + 256) * 32;
        #pragma unroll
        for (int j = 0; j < 4; j++) ra[(p + 1) & 1][j] = *(const float4*)(xbn + j * 4);
      }
      float v = db + a0.x * w0.x + a0.y * w0.y + a0.z * w0.z + a0.w * w0.w
                   + a1.x * w1.x + a1.y * w1.y + a1.z * w1.z + a1.w * w1.w
                   + a2.x * w2.x + a2.y * w2.y + a2.z * w2.z + a2.w * w2.w
                   + a3.x * w3.x + a3.y * w3.y + a3.z * w3.z + a3.w * w3.w;
      v = flog2(1.f + fexp2(v * LOG2E)) * RLOG2E;         // softplus
      v = fminf(fmaxf(v, 1e-4f), 1.0f);
      int w = (q << 1) + ((q >> 4) << 1);
      *(float2*)&sdx[w] = make_float2(v, xcl[p]);
    }
  }
  __syncthreads();

  const int pos0 = c * 16;
  const int wbase = 34 * c;                              // sdx word base for this chunk
  const float* xbp  = xBC + ((size_t)(bNp + pos0) * 32 + u * 4);
  const float* xcsp = xbp + 16;

  // ---- phase A: chunk-local h (from 0) + running dt-sum, 8-deep xb FIFO ----
  float h0 = 0.f, h1 = 0.f, h2 = 0.f, h3 = 0.f, sdt = 0.f;
  {
    float4 xbv[8];
    #pragma unroll
    for (int j = 0; j < 8; j++) xbv[j] = *(const float4*)(xbp + (size_t)j * 32);
    #pragma unroll
    for (int i = 0; i < 16; i++){
      float2 dx = *(const float2*)&sdx[wbase + 2 * i];
      float4 xb = xbv[i & 7];
      if (i < 8) xbv[i] = *(const float4*)(xbp + (size_t)(i + 8) * 32);
      float dt = dx.x, xcv = dx.y;
      sdt += dt;
      float e0 = fexp2(dt * a20), e1 = fexp2(dt * a21);
      float e2 = fexp2(dt * a22), e3 = fexp2(dt * a23);
      h0 = e0 * h0 + xb.x * xcv;
      h1 = e1 * h1 + xb.y * xcv;
      h2 = e2 * h2 + xb.z * xcv;
      h3 = e3 * h3 + xb.w * xcv;
    }
  }
  // chunk decay = exp(sum(dt)*a) ; store h, decay
  {
    float p0 = fexp2(sdt * a20), p1 = fexp2(sdt * a21);
    float p2 = fexp2(sdt * a22), p3 = fexp2(sdt * a23);
    *(float4*)&scr[c * 16 + u * 4]        = make_float4(h0, h1, h2, h3);
    *(float4*)&scr[1024 + c * 16 + u * 4] = make_float4(p0, p1, p2, p3);
  }
  __syncthreads();

  // ---- phase B: serial 64-chunk combine on 16 lanes (s = t) ----
  if (t < 16){
    float H = 0.f;
    #pragma unroll 8
    for (int cc = 0; cc < 64; cc++){
      sHin[cc * 16 + t] = H;
      H = scr[1024 + cc * 16 + t] * H + scr[cc * 16 + t];
    }
  }
  __syncthreads();

  // epilogue z load hoisted: hides HBM latency under phase C
  float4 z4 = *(const float4*)&zsp[t * 4];

  // ---- phase C: exact chain seeded with Hin; 6-deep dual-stream FIFO ----
  {
    float4 hin = *(const float4*)&sHin[c * 16 + u * 4];
    h0 = hin.x; h1 = hin.y; h2 = hin.z; h3 = hin.w;
  }
  float* yloc = scr;                 // alias (hloc/prodA dead after phase B)
  const int ybase = pos0 + ((pos0 >> 4) << 2);
  {
    float4 xbv[6], xcs6[6];
    #pragma unroll
    for (int j = 0; j < 6; j++){
      xbv[j]  = *(const float4*)(xbp  + (size_t)j * 32);
      xcs6[j] = *(const float4*)(xcsp + (size_t)j * 32);
    }
    #pragma unroll
    for (int i = 0; i < 16; i++){
      float2 dx = *(const float2*)&sdx[wbase + 2 * i];
      float4 xb  = xbv[i % 6];
      float4 xcs = xcs6[i % 6];
      if (i < 10){
        xbv[i % 6]  = *(const float4*)(xbp  + (size_t)(i + 6) * 32);
        xcs6[i % 6] = *(const float4*)(xcsp + (size_t)(i + 6) * 32);
      }
      float dt = dx.x, xcv = dx.y;
      float e0 = fexp2(dt * a20), e1 = fexp2(dt * a21);
      float e2 = fexp2(dt * a22), e3 = fexp2(dt * a23);
      h0 = e0 * h0 + xb.x * xcv;
      h1 = e1 * h1 + xb.y * xcv;
      h2 = e2 * h2 + xb.z * xcv;
      h3 = e3 * h3 + xb.w * xcv;
      float yp = h0 * xcs.x + h1 * xcs.y + h2 * xcs.z + h3 * xcs.w;
      yp = quad_sum(yp);
      if (u == 0) yloc[ybase + i] = yp;
    }
  }
  __syncthreads();

  { // epilogue: y = (scan + Dp*xc) * silu(z), packed hi/lo bf16, [e][m] layout
    int n4 = t * 4;
    const float* zp = (const float*)&z4;
    int yb = n4 + ((n4 >> 4) << 2);
    int xw = (n4 << 1) + ((n4 >> 4) << 1);
    unsigned int hpack[2], lpack[2];
    #pragma unroll
    for (int half = 0; half < 2; half++){
      unsigned int hp = 0, lp = 0;
      #pragma unroll
      for (int j = 0; j < 2; j++){
        int jj = half * 2 + j;
        float xcv = sdx[xw + 2 * jj + 1];
        float val = (yloc[yb + jj] + dpe * xcv) * zp[jj];
        unsigned short hh = f2bf(val);
        unsigned short ll = f2bf(val - bf2f(hh));
        hp |= ((unsigned int)hh) << (16 * j);
        lp |= ((unsigned int)ll) << (16 * j);
      }
      hpack[half] = hp; lpack[half] = lp;
    }
    size_t o = (size_t)e * M + bNp + n4;
    *(uint2*)&yh[o] = make_uint2(hpack[0], hpack[1]);
    *(uint2*)&yl[o] = make_uint2(lpack[0], lpack[1]);
  }
}

extern "C" void kernel_launch(void* const* d_in, const int* in_sizes, int n_in,
                              void* d_out, int out_size, void* d_ws, size_t ws_size,
                              hipStream_t stream){
  const float* px      = (const float*)d_in[0];
  const float* patch_w = (const float*)d_in[1];
  const float* patch_b = (const float*)d_in[2];
  const float* pos     = (const float*)d_in[3];
  const float* norm_w  = (const float*)d_in[4];
  const float* norm_b  = (const float*)d_in[5];
  const float* in_w    = (const float*)d_in[6];
  const float* in_b    = (const float*)d_in[7];
  const float* conv_w  = (const float*)d_in[8];
  const float* conv_b  = (const float*)d_in[9];
  const float* xp_w    = (const float*)d_in[10];
  const float* xp_b    = (const float*)d_in[11];
  const float* dt_w    = (const float*)d_in[12];
  const float* dt_b    = (const float*)d_in[13];
  const float* Aab     = (const float*)d_in[14];
  const float* Dp      = (const float*)d_in[15];
  const float* out_w   = (const float*)d_in[16];
  const float* out_b   = (const float*)d_in[17];
  const float* fnorm_w = (const float*)d_in[18];
  const float* fnorm_b = (const float*)d_in[19];
  const float* scale_w = (const float*)d_in[20];
  const float* scale_b = (const float*)d_in[21];
  float* out = (float*)d_out;

  // workspace
  float* x   = (float*)d_ws;                  // M*D
  float* xmT = x + (size_t)M * D;             // E*M f32 (transposed x_main)
  float* zst = xmT + (size_t)M * E;           // E*M
  float* xcT = zst + (size_t)M * E;           // E*M
  float* xBC = xcT + (size_t)M * E;           // M*32 ([xB|xC] halves)
  float* rs0 = xBC + (size_t)M * 32;          // M*2 LN-stats double buffer
  float* rs1 = rs0 + (size_t)M * 2;
  short* yh  = (short*)xmT;                   // E*M shorts (alias: dead x_main)
  short* yl  = yh + (size_t)M * E;
  short* pbh = yh, *pbl = yl;                 // patch buffer alias

  constexpr size_t TOTW = PW_N + IW_N + OW_N + SW_N;
  convw_kernel<<<(int)((TOTW + 255) / 256), 256, 0, stream>>>(patch_w, in_w, out_w, scale_w);
  hipMemsetAsync(xBC, 0, (size_t)M * 32 * sizeof(float), stream);   // layer-0 init
  hipMemsetAsync(rs0, 0, (size_t)M * 2 * sizeof(float), stream);    // layer-0 LN stats

  patchify_kernel<<<(M * 768 + 255) / 256, 256, 0, stream>>>(px, pbh, pbl);
  gemm_patch<<<dim3(D / 64, M / 64), 256, 0, stream>>>(pbh, pbl, patch_b, x, pos, rs0);

  for (int l = 0; l < L; l++){
    float* rs_in = (l & 1) ? rs1 : rs0;       // stats consumed by this layer's LN
    float* rs_nx = (l & 1) ? rs0 : rs1;       // stats produced for next layer
    gemm_in<<<dim3(TWO_E / 128, M / 64), 256, 0, stream>>>(
        x, rs_in, norm_w + l * D, norm_b + l * D,
        (size_t)l * TWO_E * D, in_b + l * TWO_E, xmT, zst);
    gemm_xp<<<dim3(4, M / 64), 256, 0, stream>>>(
        xmT, conv_w + (size_t)l * E * 4, conv_b + l * E,
        xp_w + (size_t)l * 32 * E, xp_b + l * 32, xcT, xBC);
    scan_kernel<<<Bz * E, 256, 0, stream>>>(
        xcT, zst, xBC, Aab + (size_t)l * E * S, Dp + l * E,
        dt_w + (size_t)l * E * S, dt_b + l * E, yh, yl, rs_nx);
    gemm_bf_at<<<dim3(D / 64, M / 64), 256, 0, stream>>>(
        yh, yl, E, (size_t)l * D * E, out_b + l * D, x, D, xBC, rs_nx);
    if (l % 4 == 0 && l / 4 < 3){
      int j = l / 4;
      gemm_scale<<<dim3(D / 64, M / 64), 256, 0, stream>>>(
          x, (size_t)j * D * D, scale_b + j * D, out + (size_t)(1 + j) * M * D);
    }
  }
  layernorm_f32<<<M / 4, 256, 0, stream>>>(x, fnorm_w, fnorm_b, out);
}

// Round 8
// 1536.670 us; speedup vs baseline: 1.0692x; 1.0692x over previous
//
#include <hip/hip_runtime.h>
#include <hip/hip_bf16.h>

// problem sizes
constexpr int Bz = 2, IMG = 512, Pp = 16, D = 384, E = 768, S = 16, L = 12;
constexpr int G = IMG / Pp;          // 32
constexpr int Np = G * G;            // 1024 patches
constexpr int M = Bz * Np;           // 2048 rows
constexpr int TWO_E = 2 * E;         // 1536

typedef short bf16x8 __attribute__((ext_vector_type(8)));
typedef float fx4    __attribute__((ext_vector_type(4)));

static __device__ __forceinline__ unsigned short f2bf(float f){
  unsigned int u = __float_as_uint(f);
  u = (u + 0x7FFFu + ((u >> 16) & 1u)) >> 16;       // RN-even
  return (unsigned short)u;
}
static __device__ __forceinline__ float bf2f(unsigned short h){
  return __uint_as_float(((unsigned int)h) << 16);
}

// fast 2^x / log2(x) via hardware transcendentals
static __device__ __forceinline__ float fexp2(float x){
  float r;
  asm("v_exp_f32 %0, %1" : "=v"(r) : "v"(x));
  return r;
}
static __device__ __forceinline__ float flog2(float x){
  float r;
  asm("v_log_f32 %0, %1" : "=v"(r) : "v"(x));
  return r;
}

// quad (4-lane) butterfly sum via DPP quad_perm
static __device__ __forceinline__ float quad_sum(float v){
  int a = __builtin_amdgcn_update_dpp(0, __float_as_int(v), 0xB1, 0xF, 0xF, true); // perm(1,0,3,2)
  v += __int_as_float(a);
  int b = __builtin_amdgcn_update_dpp(0, __float_as_int(v), 0x4E, 0xF, 0xF, true); // perm(2,3,0,1)
  v += __int_as_float(b);
  return v;
}

// ---------------- converted-weight store (device globals) ----------------
constexpr size_t PW_N = (size_t)D * 768;
constexpr size_t IW_N = (size_t)L * TWO_E * D;
constexpr size_t OW_N = (size_t)L * D * E;
constexpr size_t SW_N = (size_t)3 * D * D;
__device__ short g_pw_h[PW_N], g_pw_l[PW_N];
__device__ short g_iw_h[IW_N], g_iw_l[IW_N];
__device__ short g_ow_h[OW_N], g_ow_l[OW_N];
__device__ short g_swx_h[SW_N], g_swx_l[SW_N];

__global__ void convw_kernel(const float* __restrict__ pw, const float* __restrict__ iw,
                             const float* __restrict__ ow, const float* __restrict__ sw){
  size_t i = (size_t)blockIdx.x * 256 + threadIdx.x;
  if (i >= PW_N + IW_N + OW_N + SW_N) return;
  const float* src; short *dh, *dl; size_t j = i;
  if (j < PW_N){ src = pw; dh = g_pw_h; dl = g_pw_l; }
  else if ((j -= PW_N) < IW_N){ src = iw; dh = g_iw_h; dl = g_iw_l; }
  else if ((j -= IW_N) < OW_N){ src = ow; dh = g_ow_h; dl = g_ow_l; }
  else { j -= OW_N; src = sw; dh = g_swx_h; dl = g_swx_l; }
  float f = src[j];
  unsigned short h = f2bf(f);
  dh[j] = (short)h; dl[j] = (short)f2bf(f - bf2f(h));
}

// ---------------- patchify: pixels(f32) -> hi/lo bf16 (M x 768) ----------------
__global__ void patchify_kernel(const float* __restrict__ px,
                                short* __restrict__ oh, short* __restrict__ ol){
  int idx = blockIdx.x * 256 + threadIdx.x;
  if (idx >= M * 768) return;
  int k = idx % 768, m = idx / 768;
  int b = m / Np, n = m % Np;
  int gy = n / G, gx = n % G;
  int c = k / (Pp * Pp), r = k % (Pp * Pp);
  int py = r / Pp, pxi = r % Pp;
  size_t src = ((size_t)(b * 3 + c) * IMG + gy * Pp + py) * IMG + gx * Pp + pxi;
  float f = px[src];
  unsigned short h = f2bf(f);
  oh[idx] = (short)h; ol[idx] = (short)f2bf(f - bf2f(h));
}

// ---------------- layernorm D=384: f32 in -> hi/lo bf16 out ----------------
__global__ __launch_bounds__(256)
void layernorm_bf(const float* __restrict__ x, const float* __restrict__ w,
                  const float* __restrict__ bb, short* __restrict__ oh,
                  short* __restrict__ ol){
  int wave = threadIdx.x >> 6, lane = threadIdx.x & 63;
  int row = blockIdx.x * 4 + wave;
  const float* xr = x + (size_t)row * D;
  float v[6], s = 0.f, sq = 0.f;
  #pragma unroll
  for (int i = 0; i < 6; i++){ v[i] = xr[lane + 64 * i]; s += v[i]; sq += v[i] * v[i]; }
  #pragma unroll
  for (int off = 32; off; off >>= 1){ s += __shfl_xor(s, off); sq += __shfl_xor(sq, off); }
  float mean = s * (1.f / D);
  float var  = sq * (1.f / D) - mean * mean;
  float inv  = 1.0f / sqrtf(var + 1e-5f);
  #pragma unroll
  for (int i = 0; i < 6; i++){
    int c = lane + 64 * i;
    float o = (v[i] - mean) * inv * w[c] + bb[c];
    unsigned short h = f2bf(o);
    oh[(size_t)row * D + c] = (short)h;
    ol[(size_t)row * D + c] = (short)f2bf(o - bf2f(h));
  }
}

// ---------------- final layernorm: f32 -> f32 ----------------
__global__ __launch_bounds__(256)
void layernorm_f32(const float* __restrict__ x, const float* __restrict__ w,
                   const float* __restrict__ bb, float* __restrict__ outf){
  int wave = threadIdx.x >> 6, lane = threadIdx.x & 63;
  int row = blockIdx.x * 4 + wave;
  const float* xr = x + (size_t)row * D;
  float v[6], s = 0.f, sq = 0.f;
  #pragma unroll
  for (int i = 0; i < 6; i++){ v[i] = xr[lane + 64 * i]; s += v[i]; sq += v[i] * v[i]; }
  #pragma unroll
  for (int off = 32; off; off >>= 1){ s += __shfl_xor(s, off); sq += __shfl_xor(sq, off); }
  float mean = s * (1.f / D);
  float var  = sq * (1.f / D) - mean * mean;
  float inv  = 1.0f / sqrtf(var + 1e-5f);
  #pragma unroll
  for (int i = 0; i < 6; i++){
    int c = lane + 64 * i;
    outf[(size_t)row * D + c] = (v[i] - mean) * inv * w[c] + bb[c];
  }
}

// ---------------- in-proj MFMA GEMM, BM=64 x BN=128 (384 blocks) ----------------
__global__ __launch_bounds__(256)
void gemm_in(const short* __restrict__ Ah, const short* __restrict__ Al,
             size_t woff, const float* __restrict__ bias,
             float* __restrict__ C, float* __restrict__ C2){
  constexpr int BKp = 40;
  __shared__ __align__(16) short sAh[64 * BKp],  sAl[64 * BKp];
  __shared__ __align__(16) short sWh[128 * BKp], sWl[128 * BKp];
  const short* Wh = g_iw_h + woff;
  const short* Wl = g_iw_l + woff;
  const int t = threadIdx.x, wid = t >> 6, lane = t & 63;
  const int m0 = blockIdx.y * 64, n0 = blockIdx.x * 128;
  const int wn = wid * 32;

  fx4 acc[4][2];
  #pragma unroll
  for (int a = 0; a < 4; a++)
    #pragma unroll
    for (int b = 0; b < 2; b++)
      #pragma unroll
      for (int i = 0; i < 4; i++) acc[a][b][i] = 0.f;

  const int rA = t >> 2, kpA = (t & 3) << 3;
  const int rW = t >> 1, kpW = (t & 1) << 4;
  const int row = lane & 15, kq = lane >> 4;

  for (int kt = 0; kt < D; kt += 32){
    *(bf16x8*)&sAh[rA * BKp + kpA] = *(const bf16x8*)(Ah + (size_t)(m0 + rA) * D + kt + kpA);
    *(bf16x8*)&sAl[rA * BKp + kpA] = *(const bf16x8*)(Al + (size_t)(m0 + rA) * D + kt + kpA);
    *(bf16x8*)&sWh[rW * BKp + kpW]     = *(const bf16x8*)(Wh + (size_t)(n0 + rW) * D + kt + kpW);
    *(bf16x8*)&sWh[rW * BKp + kpW + 8] = *(const bf16x8*)(Wh + (size_t)(n0 + rW) * D + kt + kpW + 8);
    *(bf16x8*)&sWl[rW * BKp + kpW]     = *(const bf16x8*)(Wl + (size_t)(n0 + rW) * D + kt + kpW);
    *(bf16x8*)&sWl[rW * BKp + kpW + 8] = *(const bf16x8*)(Wl + (size_t)(n0 + rW) * D + kt + kpW + 8);
    __syncthreads();
    bf16x8 ah[4], al[4], bh[2], bl[2];
    #pragma unroll
    for (int tm = 0; tm < 4; tm++){
      ah[tm] = *(const bf16x8*)&sAh[(tm * 16 + row) * BKp + kq * 8];
      al[tm] = *(const bf16x8*)&sAl[(tm * 16 + row) * BKp + kq * 8];
    }
    #pragma unroll
    for (int tn = 0; tn < 2; tn++){
      bh[tn] = *(const bf16x8*)&sWh[(wn + tn * 16 + row) * BKp + kq * 8];
      bl[tn] = *(const bf16x8*)&sWl[(wn + tn * 16 + row) * BKp + kq * 8];
    }
    #pragma unroll
    for (int tm = 0; tm < 4; tm++)
      #pragma unroll
      for (int tn = 0; tn < 2; tn++){
        acc[tm][tn] = __builtin_amdgcn_mfma_f32_16x16x32_bf16(ah[tm], bh[tn], acc[tm][tn], 0, 0, 0);
        acc[tm][tn] = __builtin_amdgcn_mfma_f32_16x16x32_bf16(ah[tm], bl[tn], acc[tm][tn], 0, 0, 0);
        acc[tm][tn] = __builtin_amdgcn_mfma_f32_16x16x32_bf16(al[tm], bh[tn], acc[tm][tn], 0, 0, 0);
      }
    __syncthreads();
  }

  const int row4 = (lane >> 4) * 4, coln = lane & 15;
  #pragma unroll
  for (int tm = 0; tm < 4; tm++)
    #pragma unroll
    for (int tn = 0; tn < 2; tn++){
      int n = n0 + wn + tn * 16 + coln;
      int mb = m0 + tm * 16 + row4;
      float4 v4;
      float* vp = (float*)&v4;
      #pragma unroll
      for (int i = 0; i < 4; i++) vp[i] = acc[tm][tn][i] + bias[n];
      if (n < E){
        *(float4*)&C[(size_t)n * M + mb] = v4;          // xmT transposed
      } else {
        #pragma unroll
        for (int i = 0; i < 4; i++){
          float sig = 1.f / (1.f + expf(-vp[i]));
          vp[i] = vp[i] * sig;
        }
        *(float4*)&C2[(size_t)(n - E) * M + mb] = v4;   // zst transposed
      }
    }
}

// ---------------- patch MFMA GEMM 64x64 (pre-split A, +pos epilogue) ----------------
__global__ __launch_bounds__(256)
void gemm_patch(const short* __restrict__ Ah, const short* __restrict__ Al,
                const float* __restrict__ bias, float* __restrict__ C,
                const float* __restrict__ pos){
  constexpr int BKp = 40;
  __shared__ __align__(16) short sAh[64 * BKp], sAl[64 * BKp];
  __shared__ __align__(16) short sWh[64 * BKp], sWl[64 * BKp];
  const int t = threadIdx.x, wid = t >> 6, lane = t & 63;
  const int m0 = blockIdx.y * 64, n0 = blockIdx.x * 64;

  fx4 acc[4];
  #pragma unroll
  for (int a = 0; a < 4; a++)
    #pragma unroll
    for (int i = 0; i < 4; i++) acc[a][i] = 0.f;

  const int r = t >> 2, kp = (t & 3) << 3;
  const int row = lane & 15, kq = lane >> 4;

  for (int kt = 0; kt < 768; kt += 32){
    *(bf16x8*)&sAh[r * BKp + kp] = *(const bf16x8*)(Ah + (size_t)(m0 + r) * 768 + kt + kp);
    *(bf16x8*)&sAl[r * BKp + kp] = *(const bf16x8*)(Al + (size_t)(m0 + r) * 768 + kt + kp);
    *(bf16x8*)&sWh[r * BKp + kp] = *(const bf16x8*)(g_pw_h + (size_t)(n0 + r) * 768 + kt + kp);
    *(bf16x8*)&sWl[r * BKp + kp] = *(const bf16x8*)(g_pw_l + (size_t)(n0 + r) * 768 + kt + kp);
    __syncthreads();
    bf16x8 bh = *(const bf16x8*)&sWh[(wid * 16 + row) * BKp + kq * 8];
    bf16x8 bl = *(const bf16x8*)&sWl[(wid * 16 + row) * BKp + kq * 8];
    #pragma unroll
    for (int tm = 0; tm < 4; tm++){
      bf16x8 ah = *(const bf16x8*)&sAh[(tm * 16 + row) * BKp + kq * 8];
      bf16x8 al = *(const bf16x8*)&sAl[(tm * 16 + row) * BKp + kq * 8];
      acc[tm] = __builtin_amdgcn_mfma_f32_16x16x32_bf16(ah, bh, acc[tm], 0, 0, 0);
      acc[tm] = __builtin_amdgcn_mfma_f32_16x16x32_bf16(ah, bl, acc[tm], 0, 0, 0);
      acc[tm] = __builtin_amdgcn_mfma_f32_16x16x32_bf16(al, bh, acc[tm], 0, 0, 0);
    }
    __syncthreads();
  }

  const int row4 = (lane >> 4) * 4, coln = lane & 15;
  #pragma unroll
  for (int tm = 0; tm < 4; tm++){
    int n = n0 + wid * 16 + coln;
    int mb = m0 + tm * 16 + row4;
    #pragma unroll
    for (int i = 0; i < 4; i++){
      int m = mb + i;
      C[(size_t)m * D + n] = acc[tm][i] + bias[n] + pos[(size_t)(m & (Np - 1)) * D + n];
    }
  }
}

// ---------------- scale MFMA GEMM 64x64: A = f32 x, hi/lo converted in staging ----------------
__global__ __launch_bounds__(256)
void gemm_scale(const float* __restrict__ A, size_t woff,
                const float* __restrict__ bias, float* __restrict__ C){
  constexpr int BKp = 40;
  __shared__ __align__(16) short sAh[64 * BKp], sAl[64 * BKp];
  __shared__ __align__(16) short sWh[64 * BKp], sWl[64 * BKp];
  const short* Wh = g_swx_h + woff;
  const short* Wl = g_swx_l + woff;
  const int t = threadIdx.x, wid = t >> 6, lane = t & 63;
  const int m0 = blockIdx.y * 64, n0 = blockIdx.x * 64;

  fx4 acc[4];
  #pragma unroll
  for (int a = 0; a < 4; a++)
    #pragma unroll
    for (int i = 0; i < 4; i++) acc[a][i] = 0.f;

  const int r = t >> 2, kp = (t & 3) << 3;
  const int row = lane & 15, kq = lane >> 4;

  for (int kt = 0; kt < D; kt += 32){
    {
      const float* ap = A + (size_t)(m0 + r) * D + kt + kp;
      float4 f0 = *(const float4*)ap, f1 = *(const float4*)(ap + 4);
      float f[8] = {f0.x, f0.y, f0.z, f0.w, f1.x, f1.y, f1.z, f1.w};
      short hh[8], ll[8];
      #pragma unroll
      for (int i = 0; i < 8; i++){
        unsigned short h = f2bf(f[i]);
        hh[i] = (short)h; ll[i] = (short)f2bf(f[i] - bf2f(h));
      }
      *(bf16x8*)&sAh[r * BKp + kp] = *(bf16x8*)hh;
      *(bf16x8*)&sAl[r * BKp + kp] = *(bf16x8*)ll;
    }
    *(bf16x8*)&sWh[r * BKp + kp] = *(const bf16x8*)(Wh + (size_t)(n0 + r) * D + kt + kp);
    *(bf16x8*)&sWl[r * BKp + kp] = *(const bf16x8*)(Wl + (size_t)(n0 + r) * D + kt + kp);
    __syncthreads();
    bf16x8 bh = *(const bf16x8*)&sWh[(wid * 16 + row) * BKp + kq * 8];
    bf16x8 bl = *(const bf16x8*)&sWl[(wid * 16 + row) * BKp + kq * 8];
    #pragma unroll
    for (int tm = 0; tm < 4; tm++){
      bf16x8 ah = *(const bf16x8*)&sAh[(tm * 16 + row) * BKp + kq * 8];
      bf16x8 al = *(const bf16x8*)&sAl[(tm * 16 + row) * BKp + kq * 8];
      acc[tm] = __builtin_amdgcn_mfma_f32_16x16x32_bf16(ah, bh, acc[tm], 0, 0, 0);
      acc[tm] = __builtin_amdgcn_mfma_f32_16x16x32_bf16(ah, bl, acc[tm], 0, 0, 0);
      acc[tm] = __builtin_amdgcn_mfma_f32_16x16x32_bf16(al, bh, acc[tm], 0, 0, 0);
    }
    __syncthreads();
  }

  const int row4 = (lane >> 4) * 4, coln = lane & 15;
  #pragma unroll
  for (int tm = 0; tm < 4; tm++){
    int n = n0 + wid * 16 + coln;
    int mb = m0 + tm * 16 + row4;
    #pragma unroll
    for (int i = 0; i < 4; i++){
      int m = mb + i;
      C[(size_t)m * D + n] = acc[tm][i] + bias[n];
    }
  }
}

// ---------------- out-proj MFMA GEMM, TRANSPOSED A; epilogue: residual add + zero xBC ----------------
__global__ __launch_bounds__(256)
void gemm_bf_at(const short* __restrict__ ATh, const short* __restrict__ ATl, int K,
                size_t woff, const float* __restrict__ bias,
                float* __restrict__ C, int ncols, float* __restrict__ zbuf){
  constexpr int BKp = 40;
  __shared__ __align__(16) short sAh[64 * BKp], sAl[64 * BKp];
  __shared__ __align__(16) short sWh[64 * BKp], sWl[64 * BKp];
  const short* Wh = g_ow_h + woff;
  const short* Wl = g_ow_l + woff;
  const int t = threadIdx.x, wid = t >> 6, lane = t & 63;
  const int m0 = blockIdx.y * 64, n0 = blockIdx.x * 64;

  fx4 acc[4];
  #pragma unroll
  for (int a = 0; a < 4; a++)
    #pragma unroll
    for (int i = 0; i < 4; i++) acc[a][i] = 0.f;

  const int rw = t >> 2, kpw = (t & 3) << 3;
  const int kr2 = (t & 15) * 2, mc4 = (t >> 4) * 4;
  const int row = lane & 15, kq = lane >> 4;

  for (int kt = 0; kt < K; kt += 32){
    {
      const uint2 h0 = *(const uint2*)(ATh + (size_t)(kt + kr2) * M + m0 + mc4);
      const uint2 h1 = *(const uint2*)(ATh + (size_t)(kt + kr2 + 1) * M + m0 + mc4);
      const uint2 l0 = *(const uint2*)(ATl + (size_t)(kt + kr2) * M + m0 + mc4);
      const uint2 l1 = *(const uint2*)(ATl + (size_t)(kt + kr2 + 1) * M + m0 + mc4);
      const unsigned int h0a[2] = {h0.x, h0.y}, h1a[2] = {h1.x, h1.y};
      const unsigned int l0a[2] = {l0.x, l0.y}, l1a[2] = {l1.x, l1.y};
      #pragma unroll
      for (int j = 0; j < 4; j++){
        unsigned int s0 = (h0a[j >> 1] >> ((j & 1) * 16)) & 0xFFFFu;
        unsigned int s1 = (h1a[j >> 1] >> ((j & 1) * 16)) & 0xFFFFu;
        *(unsigned int*)&sAh[(mc4 + j) * BKp + kr2] = s0 | (s1 << 16);
        unsigned int t0 = (l0a[j >> 1] >> ((j & 1) * 16)) & 0xFFFFu;
        unsigned int t1 = (l1a[j >> 1] >> ((j & 1) * 16)) & 0xFFFFu;
        *(unsigned int*)&sAl[(mc4 + j) * BKp + kr2] = t0 | (t1 << 16);
      }
    }
    *(bf16x8*)&sWh[rw * BKp + kpw] = *(const bf16x8*)(Wh + (size_t)(n0 + rw) * K + kt + kpw);
    *(bf16x8*)&sWl[rw * BKp + kpw] = *(const bf16x8*)(Wl + (size_t)(n0 + rw) * K + kt + kpw);
    __syncthreads();
    bf16x8 bh = *(const bf16x8*)&sWh[(wid * 16 + row) * BKp + kq * 8];
    bf16x8 bl = *(const bf16x8*)&sWl[(wid * 16 + row) * BKp + kq * 8];
    #pragma unroll
    for (int tm = 0; tm < 4; tm++){
      bf16x8 ah = *(const bf16x8*)&sAh[(tm * 16 + row) * BKp + kq * 8];
      bf16x8 al = *(const bf16x8*)&sAl[(tm * 16 + row) * BKp + kq * 8];
      acc[tm] = __builtin_amdgcn_mfma_f32_16x16x32_bf16(ah, bh, acc[tm], 0, 0, 0);
      acc[tm] = __builtin_amdgcn_mfma_f32_16x16x32_bf16(ah, bl, acc[tm], 0, 0, 0);
      acc[tm] = __builtin_amdgcn_mfma_f32_16x16x32_bf16(al, bh, acc[tm], 0, 0, 0);
    }
    __syncthreads();
  }

  const int row4 = (lane >> 4) * 4, coln = lane & 15;
  #pragma unroll
  for (int tm = 0; tm < 4; tm++)
    #pragma unroll
    for (int i = 0; i < 4; i++){
      int m = m0 + tm * 16 + row4 + i;
      int n = n0 + wid * 16 + coln;
      float v = acc[tm][i] + bias[n] + C[(size_t)m * ncols + n];
      C[(size_t)m * ncols + n] = v;
    }

  // zero xBC for next layer's xp accumulation (stream order guarantees visibility)
  int gid = blockIdx.y * gridDim.x + blockIdx.x;
  int idx = gid * 256 + t;
  if (idx < M * 16)
    *(float2*)&zbuf[idx * 2] = make_float2(0.f, 0.f);
}

// ---------------- xp GEMM with FUSED depthwise conv+SiLU in A-staging ----------------
// (K-split x4, atomic): xBC [m][xB(16)|xC(16)]. Staging thread owns channel e=kt+ty and
// 4 consecutive m (tx*4); loads [m-4..m-1],[m..m+3] from xmT, computes causal 4-tap conv
// + SiLU in registers, writes both LDS As (GEMM input) and xcT (for scan). Each (e,m)
// covered exactly once across the grid -> conv_silu_t kernel deleted.
// NOTE (R7 lesson): fusions are only free when the fused grid covers each element ONCE;
// consumer-side fusion under an N-tiled grid multiplies the work by gridDim.x (LN-fusion
// regression, −105us). Producer-side/exactly-once fusions only.
__global__ __launch_bounds__(256)
void gemm_xp(const float* __restrict__ xmT, const float* __restrict__ cw,
             const float* __restrict__ cb, const float* __restrict__ W,
             const float* __restrict__ bias, float* __restrict__ xcT,
             float* __restrict__ C){
  __shared__ float As[16][68];
  __shared__ float Ws[16][32 + 1];
  int tid = threadIdx.x;
  int tx = tid & 15, ty = tid >> 4;
  int m0 = blockIdx.y * 64, kb = blockIdx.x * 192;
  float acc[4][2];
  #pragma unroll
  for (int i = 0; i < 4; i++){ acc[i][0] = 0.f; acc[i][1] = 0.f; }
  for (int kt = kb; kt < kb + 192; kt += 16){
    { // fused conv staging: channel e = kt+ty, cols m = m0 + tx*4 + j
      int e = kt + ty;
      int mbase = m0 + tx * 4;
      const float* src = xmT + (size_t)e * M + mbase;
      float4 cur = *(const float4*)src;
      float4 prv = make_float4(0.f, 0.f, 0.f, 0.f);
      if (mbase >= 4) prv = *(const float4*)(src - 4);
      float4 w4 = *(const float4*)(cw + e * 4);
      float cb_e = cb[e];
      float vin[8] = {prv.x, prv.y, prv.z, prv.w, cur.x, cur.y, cur.z, cur.w};
      float4 outv;
      float* op = (float*)&outv;
      #pragma unroll
      for (int j = 0; j < 4; j++){
        int m = mbase + j, n = m & (Np - 1);
        float a = cb_e + w4.w * vin[4 + j];
        if (n >= 1) a += w4.z * vin[3 + j];
        if (n >= 2) a += w4.y * vin[2 + j];
        if (n >= 3) a += w4.x * vin[1 + j];
        float sig = 1.f / (1.f + expf(-a));
        op[j] = a * sig;
      }
      *(float4*)&As[ty][tx * 4] = outv;
      *(float4*)&xcT[(size_t)e * M + mbase] = outv;
    }
    if (tid < 128){
      int c = tid >> 2, kk = (tid & 3) << 2;
      const float* wp = W + (size_t)c * E + kt + kk;
      Ws[kk + 0][c] = wp[0]; Ws[kk + 1][c] = wp[1];
      Ws[kk + 2][c] = wp[2]; Ws[kk + 3][c] = wp[3];
    }
    __syncthreads();
    #pragma unroll
    for (int k = 0; k < 16; k++){
      float a[4], w[2];
      #pragma unroll
      for (int i = 0; i < 4; i++) a[i] = As[k][ty * 4 + i];
      w[0] = Ws[k][tx * 2]; w[1] = Ws[k][tx * 2 + 1];
      #pragma unroll
      for (int i = 0; i < 4; i++){ acc[i][0] += a[i] * w[0]; acc[i][1] += a[i] * w[1]; }
    }
    __syncthreads();
  }
  #pragma unroll
  for (int i = 0; i < 4; i++){
    int m = m0 + ty * 4 + i;
    #pragma unroll
    for (int j = 0; j < 2; j++){
      int n = tx * 2 + j;
      float v = acc[i][j];
      if (blockIdx.x == 0) v += bias[n];
      atomicAdd(&C[(size_t)m * 32 + n], v);
    }
  }
}

// ---------------- quad-per-chunk selective scan, register-prefetch pipelined (R3-best) ----------------
// 64 chunks of 16 positions; each chunk owned by a 4-lane quad, each lane holds 4 s-values
// in registers. Phase A: chunk-local h + sum(dt), 8-deep xb register FIFO. Phase B: 64-step
// serial combine on 16 lanes (LDS-based: keeps VGPR ~20-32; register-monoid variants in
// R4/R5 pushed VGPR >64 and lost 2x occupancy — do not revisit). Phase C: exact chain
// seeded with Hin, 6-deep dual-stream FIFO, 4-FMA dot + quad DPP reduce.
// dt in [1e-4,1], A in [-16,-1] => dt*a in [-16,-1e-4]; ref's [-20,0] clip can't fire.
// softplus: log2/exp2 hw ops; overflow->inf->clamp(1.0) and underflow->0->clamp(1e-4) exact.
__global__ __launch_bounds__(256)
void scan_kernel(const float* __restrict__ xcT, const float* __restrict__ zst,
                 const float* __restrict__ xBC,
                 const float* __restrict__ Aptr, const float* __restrict__ Dp,
                 const float* __restrict__ dt_w, const float* __restrict__ dt_b,
                 short* __restrict__ yh, short* __restrict__ yl){
  __shared__ float sdx[2176];       // {dt,xcv} pairs, swizzled: word = 2*pos + 2*(pos>>4)
  __shared__ float sHin[64 * 16];   // Hin[c][s]
  __shared__ float scr[2048];       // phase A/B: hloc[0..1023] + prodA[1024..2047]; phase C alias: yloc
  const int t = threadIdx.x;
  const int c = t >> 2;             // chunk 0..63
  const int u = t & 3;              // lane-in-quad
  const int r = blockIdx.x, b = r / E, e = r % E;
  const int bNp = b * Np;
  const float dpe = Dp[e];
  constexpr float LOG2E  = 1.4426950408889634f;
  constexpr float RLOG2E = 0.6931471805599453f;
  float4 a4 = *(const float4*)(Aptr + e * S + u * 4);
  const float a20 = a4.x * LOG2E, a21 = a4.y * LOG2E, a22 = a4.z * LOG2E, a23 = a4.w * LOG2E;
  const float* xcp = xcT + (size_t)e * M + bNp;
  const float* zsp = zst + (size_t)e * M + bNp;

  { // preload: dt[pos] = clip(softplus(xB . dt_w[e] + dt_b[e])), stage {dt,xc} swizzled.
    // all 4 xcp loads upfront; xBC row loads double-buffered 2-deep; hw-transcendental softplus.
    const float* dw = dt_w + e * 16;
    float4 w0 = *(const float4*)dw,       w1 = *(const float4*)(dw + 4);
    float4 w2 = *(const float4*)(dw + 8), w3 = *(const float4*)(dw + 12);
    float db = dt_b[e];
    float xcl[4];
    #pragma unroll
    for (int p = 0; p < 4; p++) xcl[p] = xcp[t + p * 256];
    float4 ra[2][4];
    {
      const float* xb0 = xBC + (size_t)(bNp + t) * 32;
      #pragma unroll
      for (int j = 0; j < 4; j++) ra[0][j] = *(const float4*)(xb0 + j * 4);
    }
    #pragma unroll
    for (int p = 0; p < 4; p++){
      int q = t + p * 256;
      float4 a0 = ra[p & 1][0], a1 = ra[p & 1][1], a2 = ra[p & 1][2], a3 = ra[p & 1][3];
      if (p < 3){
        const float* xbn = xBC + (size_t)(bNp + q + 256) * 32;
        #pragma unroll
        for (int j = 0; j < 4; j++) ra[(p + 1) & 1][j] = *(const float4*)(xbn + j * 4);
      }
      float v = db + a0.x * w0.x + a0.y * w0.y + a0.z * w0.z + a0.w * w0.w
                   + a1.x * w1.x + a1.y * w1.y + a1.z * w1.z + a1.w * w1.w
                   + a2.x * w2.x + a2.y * w2.y + a2.z * w2.z + a2.w * w2.w
                   + a3.x * w3.x + a3.y * w3.y + a3.z * w3.z + a3.w * w3.w;
      v = flog2(1.f + fexp2(v * LOG2E)) * RLOG2E;         // softplus
      v = fminf(fmaxf(v, 1e-4f), 1.0f);
      int w = (q << 1) + ((q >> 4) << 1);
      *(float2*)&sdx[w] = make_float2(v, xcl[p]);
    }
  }
  __syncthreads();

  const int pos0 = c * 16;
  const int wbase = 34 * c;                              // sdx word base for this chunk
  const float* xbp  = xBC + ((size_t)(bNp + pos0) * 32 + u * 4);
  const float* xcsp = xbp + 16;

  // ---- phase A: chunk-local h (from 0) + running dt-sum, 8-deep xb FIFO ----
  float h0 = 0.f, h1 = 0.f, h2 = 0.f, h3 = 0.f, sdt = 0.f;
  {
    float4 xbv[8];
    #pragma unroll
    for (int j = 0; j < 8; j++) xbv[j] = *(const float4*)(xbp + (size_t)j * 32);
    #pragma unroll
    for (int i = 0; i < 16; i++){
      float2 dx = *(const float2*)&sdx[wbase + 2 * i];
      float4 xb = xbv[i & 7];
      if (i < 8) xbv[i] = *(const float4*)(xbp + (size_t)(i + 8) * 32);
      float dt = dx.x, xcv = dx.y;
      sdt += dt;
      float e0 = fexp2(dt * a20), e1 = fexp2(dt * a21);
      float e2 = fexp2(dt * a22), e3 = fexp2(dt * a23);
      h0 = e0 * h0 + xb.x * xcv;
      h1 = e1 * h1 + xb.y * xcv;
      h2 = e2 * h2 + xb.z * xcv;
      h3 = e3 * h3 + xb.w * xcv;
    }
  }
  // chunk decay = exp(sum(dt)*a) ; store h, decay
  {
    float p0 = fexp2(sdt * a20), p1 = fexp2(sdt * a21);
    float p2 = fexp2(sdt * a22), p3 = fexp2(sdt * a23);
    *(float4*)&scr[c * 16 + u * 4]        = make_float4(h0, h1, h2, h3);
    *(float4*)&scr[1024 + c * 16 + u * 4] = make_float4(p0, p1, p2, p3);
  }
  __syncthreads();

  // ---- phase B: serial 64-chunk combine on 16 lanes (s = t) ----
  if (t < 16){
    float H = 0.f;
    #pragma unroll 8
    for (int cc = 0; cc < 64; cc++){
      sHin[cc * 16 + t] = H;
      H = scr[1024 + cc * 16 + t] * H + scr[cc * 16 + t];
    }
  }
  __syncthreads();

  // epilogue z load hoisted: hides HBM latency under phase C
  float4 z4 = *(const float4*)&zsp[t * 4];

  // ---- phase C: exact chain seeded with Hin; 6-deep dual-stream FIFO ----
  {
    float4 hin = *(const float4*)&sHin[c * 16 + u * 4];
    h0 = hin.x; h1 = hin.y; h2 = hin.z; h3 = hin.w;
  }
  float* yloc = scr;                 // alias (hloc/prodA dead after phase B)
  const int ybase = pos0 + ((pos0 >> 4) << 2);
  {
    float4 xbv[6], xcs6[6];
    #pragma unroll
    for (int j = 0; j < 6; j++){
      xbv[j]  = *(const float4*)(xbp  + (size_t)j * 32);
      xcs6[j] = *(const float4*)(xcsp + (size_t)j * 32);
    }
    #pragma unroll
    for (int i = 0; i < 16; i++){
      float2 dx = *(const float2*)&sdx[wbase + 2 * i];
      float4 xb  = xbv[i % 6];
      float4 xcs = xcs6[i % 6];
      if (i < 10){
        xbv[i % 6]  = *(const float4*)(xbp  + (size_t)(i + 6) * 32);
        xcs6[i % 6] = *(const float4*)(xcsp + (size_t)(i + 6) * 32);
      }
      float dt = dx.x, xcv = dx.y;
      float e0 = fexp2(dt * a20), e1 = fexp2(dt * a21);
      float e2 = fexp2(dt * a22), e3 = fexp2(dt * a23);
      h0 = e0 * h0 + xb.x * xcv;
      h1 = e1 * h1 + xb.y * xcv;
      h2 = e2 * h2 + xb.z * xcv;
      h3 = e3 * h3 + xb.w * xcv;
      float yp = h0 * xcs.x + h1 * xcs.y + h2 * xcs.z + h3 * xcs.w;
      yp = quad_sum(yp);
      if (u == 0) yloc[ybase + i] = yp;
    }
  }
  __syncthreads();

  { // epilogue: y = (scan + Dp*xc) * silu(z), packed hi/lo bf16, [e][m] layout
    int n4 = t * 4;
    const float* zp = (const float*)&z4;
    int yb = n4 + ((n4 >> 4) << 2);
    int xw = (n4 << 1) + ((n4 >> 4) << 1);
    unsigned int hpack[2], lpack[2];
    #pragma unroll
    for (int half = 0; half < 2; half++){
      unsigned int hp = 0, lp = 0;
      #pragma unroll
      for (int j = 0; j < 2; j++){
        int jj = half * 2 + j;
        float xcv = sdx[xw + 2 * jj + 1];
        float val = (yloc[yb + jj] + dpe * xcv) * zp[jj];
        unsigned short hh = f2bf(val);
        unsigned short ll = f2bf(val - bf2f(hh));
        hp |= ((unsigned int)hh) << (16 * j);
        lp |= ((unsigned int)ll) << (16 * j);
      }
      hpack[half] = hp; lpack[half] = lp;
    }
    size_t o = (size_t)e * M + bNp + n4;
    *(uint2*)&yh[o] = make_uint2(hpack[0], hpack[1]);
    *(uint2*)&yl[o] = make_uint2(lpack[0], lpack[1]);
  }
}

extern "C" void kernel_launch(void* const* d_in, const int* in_sizes, int n_in,
                              void* d_out, int out_size, void* d_ws, size_t ws_size,
                              hipStream_t stream){
  const float* px      = (const float*)d_in[0];
  const float* patch_w = (const float*)d_in[1];
  const float* patch_b = (const float*)d_in[2];
  const float* pos     = (const float*)d_in[3];
  const float* norm_w  = (const float*)d_in[4];
  const float* norm_b  = (const float*)d_in[5];
  const float* in_w    = (const float*)d_in[6];
  const float* in_b    = (const float*)d_in[7];
  const float* conv_w  = (const float*)d_in[8];
  const float* conv_b  = (const float*)d_in[9];
  const float* xp_w    = (const float*)d_in[10];
  const float* xp_b    = (const float*)d_in[11];
  const float* dt_w    = (const float*)d_in[12];
  const float* dt_b    = (const float*)d_in[13];
  const float* Aab     = (const float*)d_in[14];
  const float* Dp      = (const float*)d_in[15];
  const float* out_w   = (const float*)d_in[16];
  const float* out_b   = (const float*)d_in[17];
  const float* fnorm_w = (const float*)d_in[18];
  const float* fnorm_b = (const float*)d_in[19];
  const float* scale_w = (const float*)d_in[20];
  const float* scale_b = (const float*)d_in[21];
  float* out = (float*)d_out;

  // workspace
  float* x   = (float*)d_ws;                  // M*D
  float* xmT = x + (size_t)M * D;             // E*M f32 (transposed x_main)
  float* zst = xmT + (size_t)M * E;           // E*M
  float* xcT = zst + (size_t)M * E;           // E*M
  float* xBC = xcT + (size_t)M * E;           // M*32 ([xB|xC] halves)
  short* xnh = (short*)(xBC + (size_t)M * 32);// M*D
  short* xnl = xnh + (size_t)M * D;           // M*D
  short* yh  = (short*)xmT;                   // E*M shorts (alias: dead x_main)
  short* yl  = yh + (size_t)M * E;
  short* pbh = yh, *pbl = yl;                 // patch buffer alias

  constexpr size_t TOTW = PW_N + IW_N + OW_N + SW_N;
  convw_kernel<<<(int)((TOTW + 255) / 256), 256, 0, stream>>>(patch_w, in_w, out_w, scale_w);
  hipMemsetAsync(xBC, 0, (size_t)M * 32 * sizeof(float), stream);   // layer-0 init

  patchify_kernel<<<(M * 768 + 255) / 256, 256, 0, stream>>>(px, pbh, pbl);
  gemm_patch<<<dim3(D / 64, M / 64), 256, 0, stream>>>(pbh, pbl, patch_b, x, pos);

  for (int l = 0; l < L; l++){
    layernorm_bf<<<M / 4, 256, 0, stream>>>(x, norm_w + l * D, norm_b + l * D, xnh, xnl);
    gemm_in<<<dim3(TWO_E / 128, M / 64), 256, 0, stream>>>(
        xnh, xnl, (size_t)l * TWO_E * D, in_b + l * TWO_E, xmT, zst);
    gemm_xp<<<dim3(4, M / 64), 256, 0, stream>>>(
        xmT, conv_w + (size_t)l * E * 4, conv_b + l * E,
        xp_w + (size_t)l * 32 * E, xp_b + l * 32, xcT, xBC);
    scan_kernel<<<Bz * E, 256, 0, stream>>>(
        xcT, zst, xBC, Aab + (size_t)l * E * S, Dp + l * E,
        dt_w + (size_t)l * E * S, dt_b + l * E, yh, yl);
    gemm_bf_at<<<dim3(D / 64, M / 64), 256, 0, stream>>>(
        yh, yl, E, (size_t)l * D * E, out_b + l * D, x, D, xBC);
    if (l % 4 == 0 && l / 4 < 3){
      int j = l / 4;
      gemm_scale<<<dim3(D / 64, M / 64), 256, 0, stream>>>(
          x, (size_t)j * D * D, scale_b + j * D, out + (size_t)(1 + j) * M * D);
    }
  }
  layernorm_f32<<<M / 4, 256, 0, stream>>>(x, fnorm_w, fnorm_b, out);
}

// Round 9
// 1407.806 us; speedup vs baseline: 1.1670x; 1.0915x over previous
//
#include <hip/hip_runtime.h>
#include <hip/hip_bf16.h>

// problem sizes
constexpr int Bz = 2, IMG = 512, Pp = 16, D = 384, E = 768, S = 16, L = 12;
constexpr int G = IMG / Pp;          // 32
constexpr int Np = G * G;            // 1024 patches
constexpr int M = Bz * Np;           // 2048 rows
constexpr int TWO_E = 2 * E;         // 1536

typedef short bf16x8 __attribute__((ext_vector_type(8)));
typedef float fx4    __attribute__((ext_vector_type(4)));

static __device__ __forceinline__ unsigned short f2bf(float f){
  unsigned int u = __float_as_uint(f);
  u = (u + 0x7FFFu + ((u >> 16) & 1u)) >> 16;       // RN-even
  return (unsigned short)u;
}
static __device__ __forceinline__ float bf2f(unsigned short h){
  return __uint_as_float(((unsigned int)h) << 16);
}

// fast 2^x / log2(x) via hardware transcendentals
static __device__ __forceinline__ float fexp2(float x){
  float r;
  asm("v_exp_f32 %0, %1" : "=v"(r) : "v"(x));
  return r;
}
static __device__ __forceinline__ float flog2(float x){
  float r;
  asm("v_log_f32 %0, %1" : "=v"(r) : "v"(x));
  return r;
}

// quad (4-lane) butterfly sum via DPP quad_perm
static __device__ __forceinline__ float quad_sum(float v){
  int a = __builtin_amdgcn_update_dpp(0, __float_as_int(v), 0xB1, 0xF, 0xF, true); // perm(1,0,3,2)
  v += __int_as_float(a);
  int b = __builtin_amdgcn_update_dpp(0, __float_as_int(v), 0x4E, 0xF, 0xF, true); // perm(2,3,0,1)
  v += __int_as_float(b);
  return v;
}

// ---------------- converted-weight store (device globals) ----------------
constexpr size_t PW_N = (size_t)D * 768;
constexpr size_t IW_N = (size_t)L * TWO_E * D;
constexpr size_t OW_N = (size_t)L * D * E;
constexpr size_t SW_N = (size_t)3 * D * D;
__device__ short g_pw_h[PW_N], g_pw_l[PW_N];
__device__ short g_iw_h[IW_N], g_iw_l[IW_N];
__device__ short g_ow_h[OW_N], g_ow_l[OW_N];
__device__ short g_swx_h[SW_N], g_swx_l[SW_N];

__global__ void convw_kernel(const float* __restrict__ pw, const float* __restrict__ iw,
                             const float* __restrict__ ow, const float* __restrict__ sw){
  size_t i = (size_t)blockIdx.x * 256 + threadIdx.x;
  if (i >= PW_N + IW_N + OW_N + SW_N) return;
  const float* src; short *dh, *dl; size_t j = i;
  if (j < PW_N){ src = pw; dh = g_pw_h; dl = g_pw_l; }
  else if ((j -= PW_N) < IW_N){ src = iw; dh = g_iw_h; dl = g_iw_l; }
  else if ((j -= IW_N) < OW_N){ src = ow; dh = g_ow_h; dl = g_ow_l; }
  else { j -= OW_N; src = sw; dh = g_swx_h; dl = g_swx_l; }
  float f = src[j];
  unsigned short h = f2bf(f);
  dh[j] = (short)h; dl[j] = (short)f2bf(f - bf2f(h));
}

// ---------------- patchify: pixels(f32) -> hi/lo bf16 (M x 768) ----------------
__global__ void patchify_kernel(const float* __restrict__ px,
                                short* __restrict__ oh, short* __restrict__ ol){
  int idx = blockIdx.x * 256 + threadIdx.x;
  if (idx >= M * 768) return;
  int k = idx % 768, m = idx / 768;
  int b = m / Np, n = m % Np;
  int gy = n / G, gx = n % G;
  int c = k / (Pp * Pp), r = k % (Pp * Pp);
  int py = r / Pp, pxi = r % Pp;
  size_t src = ((size_t)(b * 3 + c) * IMG + gy * Pp + py) * IMG + gx * Pp + pxi;
  float f = px[src];
  unsigned short h = f2bf(f);
  oh[idx] = (short)h; ol[idx] = (short)f2bf(f - bf2f(h));
}

// ---------------- layernorm D=384: f32 in -> hi/lo bf16 out ----------------
__global__ __launch_bounds__(256)
void layernorm_bf(const float* __restrict__ x, const float* __restrict__ w,
                  const float* __restrict__ bb, short* __restrict__ oh,
                  short* __restrict__ ol){
  int wave = threadIdx.x >> 6, lane = threadIdx.x & 63;
  int row = blockIdx.x * 4 + wave;
  const float* xr = x + (size_t)row * D;
  float v[6], s = 0.f, sq = 0.f;
  #pragma unroll
  for (int i = 0; i < 6; i++){ v[i] = xr[lane + 64 * i]; s += v[i]; sq += v[i] * v[i]; }
  #pragma unroll
  for (int off = 32; off; off >>= 1){ s += __shfl_xor(s, off); sq += __shfl_xor(sq, off); }
  float mean = s * (1.f / D);
  float var  = sq * (1.f / D) - mean * mean;
  float inv  = 1.0f / sqrtf(var + 1e-5f);
  #pragma unroll
  for (int i = 0; i < 6; i++){
    int c = lane + 64 * i;
    float o = (v[i] - mean) * inv * w[c] + bb[c];
    unsigned short h = f2bf(o);
    oh[(size_t)row * D + c] = (short)h;
    ol[(size_t)row * D + c] = (short)f2bf(o - bf2f(h));
  }
}

// ---------------- final layernorm: f32 -> f32 ----------------
__global__ __launch_bounds__(256)
void layernorm_f32(const float* __restrict__ x, const float* __restrict__ w,
                   const float* __restrict__ bb, float* __restrict__ outf){
  int wave = threadIdx.x >> 6, lane = threadIdx.x & 63;
  int row = blockIdx.x * 4 + wave;
  const float* xr = x + (size_t)row * D;
  float v[6], s = 0.f, sq = 0.f;
  #pragma unroll
  for (int i = 0; i < 6; i++){ v[i] = xr[lane + 64 * i]; s += v[i]; sq += v[i] * v[i]; }
  #pragma unroll
  for (int off = 32; off; off >>= 1){ s += __shfl_xor(s, off); sq += __shfl_xor(sq, off); }
  float mean = s * (1.f / D);
  float var  = sq * (1.f / D) - mean * mean;
  float inv  = 1.0f / sqrtf(var + 1e-5f);
  #pragma unroll
  for (int i = 0; i < 6; i++){
    int c = lane + 64 * i;
    outf[(size_t)row * D + c] = (v[i] - mean) * inv * w[c] + bb[c];
  }
}

// ---------------- in-proj MFMA GEMM, BM=64 x BN=64 (768 blocks = 3/CU even) ----------------
// R9: BN 128->64. 384 blocks (1.5/CU, half the CUs ran 2 serial rounds) -> 768 (3/CU even).
// Structure now matches gemm_patch's proven loop; epilogue keeps transposed writes + silu.
__global__ __launch_bounds__(256)
void gemm_in(const short* __restrict__ Ah, const short* __restrict__ Al,
             size_t woff, const float* __restrict__ bias,
             float* __restrict__ C, float* __restrict__ C2){
  constexpr int BKp = 40;
  __shared__ __align__(16) short sAh[64 * BKp], sAl[64 * BKp];
  __shared__ __align__(16) short sWh[64 * BKp], sWl[64 * BKp];
  const short* Wh = g_iw_h + woff;
  const short* Wl = g_iw_l + woff;
  const int t = threadIdx.x, wid = t >> 6, lane = t & 63;
  const int m0 = blockIdx.y * 64, n0 = blockIdx.x * 64;

  fx4 acc[4];
  #pragma unroll
  for (int a = 0; a < 4; a++)
    #pragma unroll
    for (int i = 0; i < 4; i++) acc[a][i] = 0.f;

  const int r = t >> 2, kp = (t & 3) << 3;
  const int row = lane & 15, kq = lane >> 4;

  for (int kt = 0; kt < D; kt += 32){
    *(bf16x8*)&sAh[r * BKp + kp] = *(const bf16x8*)(Ah + (size_t)(m0 + r) * D + kt + kp);
    *(bf16x8*)&sAl[r * BKp + kp] = *(const bf16x8*)(Al + (size_t)(m0 + r) * D + kt + kp);
    *(bf16x8*)&sWh[r * BKp + kp] = *(const bf16x8*)(Wh + (size_t)(n0 + r) * D + kt + kp);
    *(bf16x8*)&sWl[r * BKp + kp] = *(const bf16x8*)(Wl + (size_t)(n0 + r) * D + kt + kp);
    __syncthreads();
    bf16x8 bh = *(const bf16x8*)&sWh[(wid * 16 + row) * BKp + kq * 8];
    bf16x8 bl = *(const bf16x8*)&sWl[(wid * 16 + row) * BKp + kq * 8];
    #pragma unroll
    for (int tm = 0; tm < 4; tm++){
      bf16x8 ah = *(const bf16x8*)&sAh[(tm * 16 + row) * BKp + kq * 8];
      bf16x8 al = *(const bf16x8*)&sAl[(tm * 16 + row) * BKp + kq * 8];
      acc[tm] = __builtin_amdgcn_mfma_f32_16x16x32_bf16(ah, bh, acc[tm], 0, 0, 0);
      acc[tm] = __builtin_amdgcn_mfma_f32_16x16x32_bf16(ah, bl, acc[tm], 0, 0, 0);
      acc[tm] = __builtin_amdgcn_mfma_f32_16x16x32_bf16(al, bh, acc[tm], 0, 0, 0);
    }
    __syncthreads();
  }

  const int row4 = (lane >> 4) * 4, coln = lane & 15;
  #pragma unroll
  for (int tm = 0; tm < 4; tm++){
    int n = n0 + wid * 16 + coln;
    int mb = m0 + tm * 16 + row4;
    float4 v4;
    float* vp = (float*)&v4;
    #pragma unroll
    for (int i = 0; i < 4; i++) vp[i] = acc[tm][i] + bias[n];
    if (n < E){
      *(float4*)&C[(size_t)n * M + mb] = v4;          // xmT transposed
    } else {
      #pragma unroll
      for (int i = 0; i < 4; i++){
        float sig = 1.f / (1.f + expf(-vp[i]));
        vp[i] = vp[i] * sig;
      }
      *(float4*)&C2[(size_t)(n - E) * M + mb] = v4;   // zst transposed
    }
  }
}

// ---------------- patch MFMA GEMM 64x64 (pre-split A, +pos epilogue) ----------------
__global__ __launch_bounds__(256)
void gemm_patch(const short* __restrict__ Ah, const short* __restrict__ Al,
                const float* __restrict__ bias, float* __restrict__ C,
                const float* __restrict__ pos){
  constexpr int BKp = 40;
  __shared__ __align__(16) short sAh[64 * BKp], sAl[64 * BKp];
  __shared__ __align__(16) short sWh[64 * BKp], sWl[64 * BKp];
  const int t = threadIdx.x, wid = t >> 6, lane = t & 63;
  const int m0 = blockIdx.y * 64, n0 = blockIdx.x * 64;

  fx4 acc[4];
  #pragma unroll
  for (int a = 0; a < 4; a++)
    #pragma unroll
    for (int i = 0; i < 4; i++) acc[a][i] = 0.f;

  const int r = t >> 2, kp = (t & 3) << 3;
  const int row = lane & 15, kq = lane >> 4;

  for (int kt = 0; kt < 768; kt += 32){
    *(bf16x8*)&sAh[r * BKp + kp] = *(const bf16x8*)(Ah + (size_t)(m0 + r) * 768 + kt + kp);
    *(bf16x8*)&sAl[r * BKp + kp] = *(const bf16x8*)(Al + (size_t)(m0 + r) * 768 + kt + kp);
    *(bf16x8*)&sWh[r * BKp + kp] = *(const bf16x8*)(g_pw_h + (size_t)(n0 + r) * 768 + kt + kp);
    *(bf16x8*)&sWl[r * BKp + kp] = *(const bf16x8*)(g_pw_l + (size_t)(n0 + r) * 768 + kt + kp);
    __syncthreads();
    bf16x8 bh = *(const bf16x8*)&sWh[(wid * 16 + row) * BKp + kq * 8];
    bf16x8 bl = *(const bf16x8*)&sWl[(wid * 16 + row) * BKp + kq * 8];
    #pragma unroll
    for (int tm = 0; tm < 4; tm++){
      bf16x8 ah = *(const bf16x8*)&sAh[(tm * 16 + row) * BKp + kq * 8];
      bf16x8 al = *(const bf16x8*)&sAl[(tm * 16 + row) * BKp + kq * 8];
      acc[tm] = __builtin_amdgcn_mfma_f32_16x16x32_bf16(ah, bh, acc[tm], 0, 0, 0);
      acc[tm] = __builtin_amdgcn_mfma_f32_16x16x32_bf16(ah, bl, acc[tm], 0, 0, 0);
      acc[tm] = __builtin_amdgcn_mfma_f32_16x16x32_bf16(al, bh, acc[tm], 0, 0, 0);
    }
    __syncthreads();
  }

  const int row4 = (lane >> 4) * 4, coln = lane & 15;
  #pragma unroll
  for (int tm = 0; tm < 4; tm++){
    int n = n0 + wid * 16 + coln;
    int mb = m0 + tm * 16 + row4;
    #pragma unroll
    for (int i = 0; i < 4; i++){
      int m = mb + i;
      C[(size_t)m * D + n] = acc[tm][i] + bias[n] + pos[(size_t)(m & (Np - 1)) * D + n];
    }
  }
}

// ---------------- scale MFMA GEMM 64x64: A = f32 x, hi/lo converted in staging ----------------
__global__ __launch_bounds__(256)
void gemm_scale(const float* __restrict__ A, size_t woff,
                const float* __restrict__ bias, float* __restrict__ C){
  constexpr int BKp = 40;
  __shared__ __align__(16) short sAh[64 * BKp], sAl[64 * BKp];
  __shared__ __align__(16) short sWh[64 * BKp], sWl[64 * BKp];
  const short* Wh = g_swx_h + woff;
  const short* Wl = g_swx_l + woff;
  const int t = threadIdx.x, wid = t >> 6, lane = t & 63;
  const int m0 = blockIdx.y * 64, n0 = blockIdx.x * 64;

  fx4 acc[4];
  #pragma unroll
  for (int a = 0; a < 4; a++)
    #pragma unroll
    for (int i = 0; i < 4; i++) acc[a][i] = 0.f;

  const int r = t >> 2, kp = (t & 3) << 3;
  const int row = lane & 15, kq = lane >> 4;

  for (int kt = 0; kt < D; kt += 32){
    {
      const float* ap = A + (size_t)(m0 + r) * D + kt + kp;
      float4 f0 = *(const float4*)ap, f1 = *(const float4*)(ap + 4);
      float f[8] = {f0.x, f0.y, f0.z, f0.w, f1.x, f1.y, f1.z, f1.w};
      short hh[8], ll[8];
      #pragma unroll
      for (int i = 0; i < 8; i++){
        unsigned short h = f2bf(f[i]);
        hh[i] = (short)h; ll[i] = (short)f2bf(f[i] - bf2f(h));
      }
      *(bf16x8*)&sAh[r * BKp + kp] = *(bf16x8*)hh;
      *(bf16x8*)&sAl[r * BKp + kp] = *(bf16x8*)ll;
    }
    *(bf16x8*)&sWh[r * BKp + kp] = *(const bf16x8*)(Wh + (size_t)(n0 + r) * D + kt + kp);
    *(bf16x8*)&sWl[r * BKp + kp] = *(const bf16x8*)(Wl + (size_t)(n0 + r) * D + kt + kp);
    __syncthreads();
    bf16x8 bh = *(const bf16x8*)&sWh[(wid * 16 + row) * BKp + kq * 8];
    bf16x8 bl = *(const bf16x8*)&sWl[(wid * 16 + row) * BKp + kq * 8];
    #pragma unroll
    for (int tm = 0; tm < 4; tm++){
      bf16x8 ah = *(const bf16x8*)&sAh[(tm * 16 + row) * BKp + kq * 8];
      bf16x8 al = *(const bf16x8*)&sAl[(tm * 16 + row) * BKp + kq * 8];
      acc[tm] = __builtin_amdgcn_mfma_f32_16x16x32_bf16(ah, bh, acc[tm], 0, 0, 0);
      acc[tm] = __builtin_amdgcn_mfma_f32_16x16x32_bf16(ah, bl, acc[tm], 0, 0, 0);
      acc[tm] = __builtin_amdgcn_mfma_f32_16x16x32_bf16(al, bh, acc[tm], 0, 0, 0);
    }
    __syncthreads();
  }

  const int row4 = (lane >> 4) * 4, coln = lane & 15;
  #pragma unroll
  for (int tm = 0; tm < 4; tm++){
    int n = n0 + wid * 16 + coln;
    int mb = m0 + tm * 16 + row4;
    #pragma unroll
    for (int i = 0; i < 4; i++){
      int m = mb + i;
      C[(size_t)m * D + n] = acc[tm][i] + bias[n];
    }
  }
}

// ---------------- out-proj MFMA GEMM, TRANSPOSED A; epilogue: residual add + zero xBC ----------------
__global__ __launch_bounds__(256)
void gemm_bf_at(const short* __restrict__ ATh, const short* __restrict__ ATl, int K,
                size_t woff, const float* __restrict__ bias,
                float* __restrict__ C, int ncols, float* __restrict__ zbuf){
  constexpr int BKp = 40;
  __shared__ __align__(16) short sAh[64 * BKp], sAl[64 * BKp];
  __shared__ __align__(16) short sWh[64 * BKp], sWl[64 * BKp];
  const short* Wh = g_ow_h + woff;
  const short* Wl = g_ow_l + woff;
  const int t = threadIdx.x, wid = t >> 6, lane = t & 63;
  const int m0 = blockIdx.y * 64, n0 = blockIdx.x * 64;

  fx4 acc[4];
  #pragma unroll
  for (int a = 0; a < 4; a++)
    #pragma unroll
    for (int i = 0; i < 4; i++) acc[a][i] = 0.f;

  const int rw = t >> 2, kpw = (t & 3) << 3;
  const int kr2 = (t & 15) * 2, mc4 = (t >> 4) * 4;
  const int row = lane & 15, kq = lane >> 4;

  for (int kt = 0; kt < K; kt += 32){
    {
      const uint2 h0 = *(const uint2*)(ATh + (size_t)(kt + kr2) * M + m0 + mc4);
      const uint2 h1 = *(const uint2*)(ATh + (size_t)(kt + kr2 + 1) * M + m0 + mc4);
      const uint2 l0 = *(const uint2*)(ATl + (size_t)(kt + kr2) * M + m0 + mc4);
      const uint2 l1 = *(const uint2*)(ATl + (size_t)(kt + kr2 + 1) * M + m0 + mc4);
      const unsigned int h0a[2] = {h0.x, h0.y}, h1a[2] = {h1.x, h1.y};
      const unsigned int l0a[2] = {l0.x, l0.y}, l1a[2] = {l1.x, l1.y};
      #pragma unroll
      for (int j = 0; j < 4; j++){
        unsigned int s0 = (h0a[j >> 1] >> ((j & 1) * 16)) & 0xFFFFu;
        unsigned int s1 = (h1a[j >> 1] >> ((j & 1) * 16)) & 0xFFFFu;
        *(unsigned int*)&sAh[(mc4 + j) * BKp + kr2] = s0 | (s1 << 16);
        unsigned int t0 = (l0a[j >> 1] >> ((j & 1) * 16)) & 0xFFFFu;
        unsigned int t1 = (l1a[j >> 1] >> ((j & 1) * 16)) & 0xFFFFu;
        *(unsigned int*)&sAl[(mc4 + j) * BKp + kr2] = t0 | (t1 << 16);
      }
    }
    *(bf16x8*)&sWh[rw * BKp + kpw] = *(const bf16x8*)(Wh + (size_t)(n0 + rw) * K + kt + kpw);
    *(bf16x8*)&sWl[rw * BKp + kpw] = *(const bf16x8*)(Wl + (size_t)(n0 + rw) * K + kt + kpw);
    __syncthreads();
    bf16x8 bh = *(const bf16x8*)&sWh[(wid * 16 + row) * BKp + kq * 8];
    bf16x8 bl = *(const bf16x8*)&sWl[(wid * 16 + row) * BKp + kq * 8];
    #pragma unroll
    for (int tm = 0; tm < 4; tm++){
      bf16x8 ah = *(const bf16x8*)&sAh[(tm * 16 + row) * BKp + kq * 8];
      bf16x8 al = *(const bf16x8*)&sAl[(tm * 16 + row) * BKp + kq * 8];
      acc[tm] = __builtin_amdgcn_mfma_f32_16x16x32_bf16(ah, bh, acc[tm], 0, 0, 0);
      acc[tm] = __builtin_amdgcn_mfma_f32_16x16x32_bf16(ah, bl, acc[tm], 0, 0, 0);
      acc[tm] = __builtin_amdgcn_mfma_f32_16x16x32_bf16(al, bh, acc[tm], 0, 0, 0);
    }
    __syncthreads();
  }

  const int row4 = (lane >> 4) * 4, coln = lane & 15;
  #pragma unroll
  for (int tm = 0; tm < 4; tm++)
    #pragma unroll
    for (int i = 0; i < 4; i++){
      int m = m0 + tm * 16 + row4 + i;
      int n = n0 + wid * 16 + coln;
      float v = acc[tm][i] + bias[n] + C[(size_t)m * ncols + n];
      C[(size_t)m * ncols + n] = v;
    }

  // zero xBC for next layer's xp accumulation (stream order guarantees visibility)
  int gid = blockIdx.y * gridDim.x + blockIdx.x;
  int idx = gid * 256 + t;
  if (idx < M * 16)
    *(float2*)&zbuf[idx * 2] = make_float2(0.f, 0.f);
}

// ---------------- xp GEMM with FUSED depthwise conv+SiLU in A-staging ----------------
// R9: K-split 4->8 (96 channels/block) -> 256 blocks = 1/CU even (was 128 = half machine idle).
// Staging thread owns channel e=kt+ty and 4 consecutive m; computes causal conv+SiLU in regs,
// writes both LDS As (GEMM input) and xcT (for scan). Each (e,m) covered exactly once.
// NOTE (R7 lesson): fusions only free when fused grid covers each element ONCE.
__global__ __launch_bounds__(256)
void gemm_xp(const float* __restrict__ xmT, const float* __restrict__ cw,
             const float* __restrict__ cb, const float* __restrict__ W,
             const float* __restrict__ bias, float* __restrict__ xcT,
             float* __restrict__ C){
  __shared__ float As[16][68];
  __shared__ float Ws[16][32 + 1];
  int tid = threadIdx.x;
  int tx = tid & 15, ty = tid >> 4;
  int m0 = blockIdx.y * 64, kb = blockIdx.x * 96;
  float acc[4][2];
  #pragma unroll
  for (int i = 0; i < 4; i++){ acc[i][0] = 0.f; acc[i][1] = 0.f; }
  for (int kt = kb; kt < kb + 96; kt += 16){
    { // fused conv staging: channel e = kt+ty, cols m = m0 + tx*4 + j
      int e = kt + ty;
      int mbase = m0 + tx * 4;
      const float* src = xmT + (size_t)e * M + mbase;
      float4 cur = *(const float4*)src;
      float4 prv = make_float4(0.f, 0.f, 0.f, 0.f);
      if (mbase >= 4) prv = *(const float4*)(src - 4);
      float4 w4 = *(const float4*)(cw + e * 4);
      float cb_e = cb[e];
      float vin[8] = {prv.x, prv.y, prv.z, prv.w, cur.x, cur.y, cur.z, cur.w};
      float4 outv;
      float* op = (float*)&outv;
      #pragma unroll
      for (int j = 0; j < 4; j++){
        int m = mbase + j, n = m & (Np - 1);
        float a = cb_e + w4.w * vin[4 + j];
        if (n >= 1) a += w4.z * vin[3 + j];
        if (n >= 2) a += w4.y * vin[2 + j];
        if (n >= 3) a += w4.x * vin[1 + j];
        float sig = 1.f / (1.f + expf(-a));
        op[j] = a * sig;
      }
      *(float4*)&As[ty][tx * 4] = outv;
      *(float4*)&xcT[(size_t)e * M + mbase] = outv;
    }
    if (tid < 128){
      int c = tid >> 2, kk = (tid & 3) << 2;
      const float* wp = W + (size_t)c * E + kt + kk;
      Ws[kk + 0][c] = wp[0]; Ws[kk + 1][c] = wp[1];
      Ws[kk + 2][c] = wp[2]; Ws[kk + 3][c] = wp[3];
    }
    __syncthreads();
    #pragma unroll
    for (int k = 0; k < 16; k++){
      float a[4], w[2];
      #pragma unroll
      for (int i = 0; i < 4; i++) a[i] = As[k][ty * 4 + i];
      w[0] = Ws[k][tx * 2]; w[1] = Ws[k][tx * 2 + 1];
      #pragma unroll
      for (int i = 0; i < 4; i++){ acc[i][0] += a[i] * w[0]; acc[i][1] += a[i] * w[1]; }
    }
    __syncthreads();
  }
  #pragma unroll
  for (int i = 0; i < 4; i++){
    int m = m0 + ty * 4 + i;
    #pragma unroll
    for (int j = 0; j < 2; j++){
      int n = tx * 2 + j;
      float v = acc[i][j];
      if (blockIdx.x == 0) v += bias[n];
      atomicAdd(&C[(size_t)m * 32 + n], v);
    }
  }
}

// ---------------- quad-per-chunk selective scan, register-prefetch pipelined (R3-best) ----------------
// 64 chunks of 16 positions; each chunk owned by a 4-lane quad, each lane holds 4 s-values
// in registers. Phase A: chunk-local h + sum(dt), 8-deep xb register FIFO. Phase B: 64-step
// serial combine on 16 lanes (LDS-based: keeps VGPR ~20-32; register-monoid variants in
// R4/R5 pushed VGPR >64 and lost 2x occupancy — do not revisit). Phase C: exact chain
// seeded with Hin, 6-deep dual-stream FIFO, 4-FMA dot + quad DPP reduce.
// dt in [1e-4,1], A in [-16,-1] => dt*a in [-16,-1e-4]; ref's [-20,0] clip can't fire.
// softplus: log2/exp2 hw ops; overflow->inf->clamp(1.0) and underflow->0->clamp(1e-4) exact.
__global__ __launch_bounds__(256)
void scan_kernel(const float* __restrict__ xcT, const float* __restrict__ zst,
                 const float* __restrict__ xBC,
                 const float* __restrict__ Aptr, const float* __restrict__ Dp,
                 const float* __restrict__ dt_w, const float* __restrict__ dt_b,
                 short* __restrict__ yh, short* __restrict__ yl){
  __shared__ float sdx[2176];       // {dt,xcv} pairs, swizzled: word = 2*pos + 2*(pos>>4)
  __shared__ float sHin[64 * 16];   // Hin[c][s]
  __shared__ float scr[2048];       // phase A/B: hloc[0..1023] + prodA[1024..2047]; phase C alias: yloc
  const int t = threadIdx.x;
  const int c = t >> 2;             // chunk 0..63
  const int u = t & 3;              // lane-in-quad
  const int r = blockIdx.x, b = r / E, e = r % E;
  const int bNp = b * Np;
  const float dpe = Dp[e];
  constexpr float LOG2E  = 1.4426950408889634f;
  constexpr float RLOG2E = 0.6931471805599453f;
  float4 a4 = *(const float4*)(Aptr + e * S + u * 4);
  const float a20 = a4.x * LOG2E, a21 = a4.y * LOG2E, a22 = a4.z * LOG2E, a23 = a4.w * LOG2E;
  const float* xcp = xcT + (size_t)e * M + bNp;
  const float* zsp = zst + (size_t)e * M + bNp;

  { // preload: dt[pos] = clip(softplus(xB . dt_w[e] + dt_b[e])), stage {dt,xc} swizzled.
    // all 4 xcp loads upfront; xBC row loads double-buffered 2-deep; hw-transcendental softplus.
    const float* dw = dt_w + e * 16;
    float4 w0 = *(const float4*)dw,       w1 = *(const float4*)(dw + 4);
    float4 w2 = *(const float4*)(dw + 8), w3 = *(const float4*)(dw + 12);
    float db = dt_b[e];
    float xcl[4];
    #pragma unroll
    for (int p = 0; p < 4; p++) xcl[p] = xcp[t + p * 256];
    float4 ra[2][4];
    {
      const float* xb0 = xBC + (size_t)(bNp + t) * 32;
      #pragma unroll
      for (int j = 0; j < 4; j++) ra[0][j] = *(const float4*)(xb0 + j * 4);
    }
    #pragma unroll
    for (int p = 0; p < 4; p++){
      int q = t + p * 256;
      float4 a0 = ra[p & 1][0], a1 = ra[p & 1][1], a2 = ra[p & 1][2], a3 = ra[p & 1][3];
      if (p < 3){
        const float* xbn = xBC + (size_t)(bNp + q + 256) * 32;
        #pragma unroll
        for (int j = 0; j < 4; j++) ra[(p + 1) & 1][j] = *(const float4*)(xbn + j * 4);
      }
      float v = db + a0.x * w0.x + a0.y * w0.y + a0.z * w0.z + a0.w * w0.w
                   + a1.x * w1.x + a1.y * w1.y + a1.z * w1.z + a1.w * w1.w
                   + a2.x * w2.x + a2.y * w2.y + a2.z * w2.z + a2.w * w2.w
                   + a3.x * w3.x + a3.y * w3.y + a3.z * w3.z + a3.w * w3.w;
      v = flog2(1.f + fexp2(v * LOG2E)) * RLOG2E;         // softplus
      v = fminf(fmaxf(v, 1e-4f), 1.0f);
      int w = (q << 1) + ((q >> 4) << 1);
      *(float2*)&sdx[w] = make_float2(v, xcl[p]);
    }
  }
  __syncthreads();

  const int pos0 = c * 16;
  const int wbase = 34 * c;                              // sdx word base for this chunk
  const float* xbp  = xBC + ((size_t)(bNp + pos0) * 32 + u * 4);
  const float* xcsp = xbp + 16;

  // ---- phase A: chunk-local h (from 0) + running dt-sum, 8-deep xb FIFO ----
  float h0 = 0.f, h1 = 0.f, h2 = 0.f, h3 = 0.f, sdt = 0.f;
  {
    float4 xbv[8];
    #pragma unroll
    for (int j = 0; j < 8; j++) xbv[j] = *(const float4*)(xbp + (size_t)j * 32);
    #pragma unroll
    for (int i = 0; i < 16; i++){
      float2 dx = *(const float2*)&sdx[wbase + 2 * i];
      float4 xb = xbv[i & 7];
      if (i < 8) xbv[i] = *(const float4*)(xbp + (size_t)(i + 8) * 32);
      float dt = dx.x, xcv = dx.y;
      sdt += dt;
      float e0 = fexp2(dt * a20), e1 = fexp2(dt * a21);
      float e2 = fexp2(dt * a22), e3 = fexp2(dt * a23);
      h0 = e0 * h0 + xb.x * xcv;
      h1 = e1 * h1 + xb.y * xcv;
      h2 = e2 * h2 + xb.z * xcv;
      h3 = e3 * h3 + xb.w * xcv;
    }
  }
  // chunk decay = exp(sum(dt)*a) ; store h, decay
  {
    float p0 = fexp2(sdt * a20), p1 = fexp2(sdt * a21);
    float p2 = fexp2(sdt * a22), p3 = fexp2(sdt * a23);
    *(float4*)&scr[c * 16 + u * 4]        = make_float4(h0, h1, h2, h3);
    *(float4*)&scr[1024 + c * 16 + u * 4] = make_float4(p0, p1, p2, p3);
  }
  __syncthreads();

  // ---- phase B: serial 64-chunk combine on 16 lanes (s = t) ----
  if (t < 16){
    float H = 0.f;
    #pragma unroll 8
    for (int cc = 0; cc < 64; cc++){
      sHin[cc * 16 + t] = H;
      H = scr[1024 + cc * 16 + t] * H + scr[cc * 16 + t];
    }
  }
  __syncthreads();

  // epilogue z load hoisted: hides HBM latency under phase C
  float4 z4 = *(const float4*)&zsp[t * 4];

  // ---- phase C: exact chain seeded with Hin; 6-deep dual-stream FIFO ----
  {
    float4 hin = *(const float4*)&sHin[c * 16 + u * 4];
    h0 = hin.x; h1 = hin.y; h2 = hin.z; h3 = hin.w;
  }
  float* yloc = scr;                 // alias (hloc/prodA dead after phase B)
  const int ybase = pos0 + ((pos0 >> 4) << 2);
  {
    float4 xbv[6], xcs6[6];
    #pragma unroll
    for (int j = 0; j < 6; j++){
      xbv[j]  = *(const float4*)(xbp  + (size_t)j * 32);
      xcs6[j] = *(const float4*)(xcsp + (size_t)j * 32);
    }
    #pragma unroll
    for (int i = 0; i < 16; i++){
      float2 dx = *(const float2*)&sdx[wbase + 2 * i];
      float4 xb  = xbv[i % 6];
      float4 xcs = xcs6[i % 6];
      if (i < 10){
        xbv[i % 6]  = *(const float4*)(xbp  + (size_t)(i + 6) * 32);
        xcs6[i % 6] = *(const float4*)(xcsp + (size_t)(i + 6) * 32);
      }
      float dt = dx.x, xcv = dx.y;
      float e0 = fexp2(dt * a20), e1 = fexp2(dt * a21);
      float e2 = fexp2(dt * a22), e3 = fexp2(dt * a23);
      h0 = e0 * h0 + xb.x * xcv;
      h1 = e1 * h1 + xb.y * xcv;
      h2 = e2 * h2 + xb.z * xcv;
      h3 = e3 * h3 + xb.w * xcv;
      float yp = h0 * xcs.x + h1 * xcs.y + h2 * xcs.z + h3 * xcs.w;
      yp = quad_sum(yp);
      if (u == 0) yloc[ybase + i] = yp;
    }
  }
  __syncthreads();

  { // epilogue: y = (scan + Dp*xc) * silu(z), packed hi/lo bf16, [e][m] layout
    int n4 = t * 4;
    const float* zp = (const float*)&z4;
    int yb = n4 + ((n4 >> 4) << 2);
    int xw = (n4 << 1) + ((n4 >> 4) << 1);
    unsigned int hpack[2], lpack[2];
    #pragma unroll
    for (int half = 0; half < 2; half++){
      unsigned int hp = 0, lp = 0;
      #pragma unroll
      for (int j = 0; j < 2; j++){
        int jj = half * 2 + j;
        float xcv = sdx[xw + 2 * jj + 1];
        float val = (yloc[yb + jj] + dpe * xcv) * zp[jj];
        unsigned short hh = f2bf(val);
        unsigned short ll = f2bf(val - bf2f(hh));
        hp |= ((unsigned int)hh) << (16 * j);
        lp |= ((unsigned int)ll) << (16 * j);
      }
      hpack[half] = hp; lpack[half] = lp;
    }
    size_t o = (size_t)e * M + bNp + n4;
    *(uint2*)&yh[o] = make_uint2(hpack[0], hpack[1]);
    *(uint2*)&yl[o] = make_uint2(lpack[0], lpack[1]);
  }
}

extern "C" void kernel_launch(void* const* d_in, const int* in_sizes, int n_in,
                              void* d_out, int out_size, void* d_ws, size_t ws_size,
                              hipStream_t stream){
  const float* px      = (const float*)d_in[0];
  const float* patch_w = (const float*)d_in[1];
  const float* patch_b = (const float*)d_in[2];
  const float* pos     = (const float*)d_in[3];
  const float* norm_w  = (const float*)d_in[4];
  const float* norm_b  = (const float*)d_in[5];
  const float* in_w    = (const float*)d_in[6];
  const float* in_b    = (const float*)d_in[7];
  const float* conv_w  = (const float*)d_in[8];
  const float* conv_b  = (const float*)d_in[9];
  const float* xp_w    = (const float*)d_in[10];
  const float* xp_b    = (const float*)d_in[11];
  const float* dt_w    = (const float*)d_in[12];
  const float* dt_b    = (const float*)d_in[13];
  const float* Aab     = (const float*)d_in[14];
  const float* Dp      = (const float*)d_in[15];
  const float* out_w   = (const float*)d_in[16];
  const float* out_b   = (const float*)d_in[17];
  const float* fnorm_w = (const float*)d_in[18];
  const float* fnorm_b = (const float*)d_in[19];
  const float* scale_w = (const float*)d_in[20];
  const float* scale_b = (const float*)d_in[21];
  float* out = (float*)d_out;

  // workspace
  float* x   = (float*)d_ws;                  // M*D
  float* xmT = x + (size_t)M * D;             // E*M f32 (transposed x_main)
  float* zst = xmT + (size_t)M * E;           // E*M
  float* xcT = zst + (size_t)M * E;           // E*M
  float* xBC = xcT + (size_t)M * E;           // M*32 ([xB|xC] halves)
  short* xnh = (short*)(xBC + (size_t)M * 32);// M*D
  short* xnl = xnh + (size_t)M * D;           // M*D
  short* yh  = (short*)xmT;                   // E*M shorts (alias: dead x_main)
  short* yl  = yh + (size_t)M * E;
  short* pbh = yh, *pbl = yl;                 // patch buffer alias

  constexpr size_t TOTW = PW_N + IW_N + OW_N + SW_N;
  convw_kernel<<<(int)((TOTW + 255) / 256), 256, 0, stream>>>(patch_w, in_w, out_w, scale_w);
  hipMemsetAsync(xBC, 0, (size_t)M * 32 * sizeof(float), stream);   // layer-0 init

  patchify_kernel<<<(M * 768 + 255) / 256, 256, 0, stream>>>(px, pbh, pbl);
  gemm_patch<<<dim3(D / 64, M / 64), 256, 0, stream>>>(pbh, pbl, patch_b, x, pos);

  for (int l = 0; l < L; l++){
    layernorm_bf<<<M / 4, 256, 0, stream>>>(x, norm_w + l * D, norm_b + l * D, xnh, xnl);
    gemm_in<<<dim3(TWO_E / 64, M / 64), 256, 0, stream>>>(
        xnh, xnl, (size_t)l * TWO_E * D, in_b + l * TWO_E, xmT, zst);
    gemm_xp<<<dim3(8, M / 64), 256, 0, stream>>>(
        xmT, conv_w + (size_t)l * E * 4, conv_b + l * E,
        xp_w + (size_t)l * 32 * E, xp_b + l * 32, xcT, xBC);
    scan_kernel<<<Bz * E, 256, 0, stream>>>(
        xcT, zst, xBC, Aab + (size_t)l * E * S, Dp + l * E,
        dt_w + (size_t)l * E * S, dt_b + l * E, yh, yl);
    gemm_bf_at<<<dim3(D / 64, M / 64), 256, 0, stream>>>(
        yh, yl, E, (size_t)l * D * E, out_b + l * D, x, D, xBC);
    if (l % 4 == 0 && l / 4 < 3){
      int j = l / 4;
      gemm_scale<<<dim3(D / 64, M / 64), 256, 0, stream>>>(
          x, (size_t)j * D * D, scale_b + j * D, out + (size_t)(1 + j) * M * D);
    }
  }
  layernorm_f32<<<M / 4, 256, 0, stream>>>(x, fnorm_w, fnorm_b, out);
}

// Round 10
// 1323.590 us; speedup vs baseline: 1.2413x; 1.0636x over previous
//
#include <hip/hip_runtime.h>
#include <hip/hip_bf16.h>

// problem sizes
constexpr int Bz = 2, IMG = 512, Pp = 16, D = 384, E = 768, S = 16, L = 12;
constexpr int G = IMG / Pp;          // 32
constexpr int Np = G * G;            // 1024 patches
constexpr int M = Bz * Np;           // 2048 rows
constexpr int TWO_E = 2 * E;         // 1536

typedef short bf16x8 __attribute__((ext_vector_type(8)));
typedef float fx4    __attribute__((ext_vector_type(4)));

static __device__ __forceinline__ unsigned short f2bf(float f){
  unsigned int u = __float_as_uint(f);
  u = (u + 0x7FFFu + ((u >> 16) & 1u)) >> 16;       // RN-even
  return (unsigned short)u;
}
static __device__ __forceinline__ float bf2f(unsigned short h){
  return __uint_as_float(((unsigned int)h) << 16);
}

// fast 2^x / log2(x) via hardware transcendentals
static __device__ __forceinline__ float fexp2(float x){
  float r;
  asm("v_exp_f32 %0, %1" : "=v"(r) : "v"(x));
  return r;
}
static __device__ __forceinline__ float flog2(float x){
  float r;
  asm("v_log_f32 %0, %1" : "=v"(r) : "v"(x));
  return r;
}

// quad (4-lane) butterfly sum via DPP quad_perm
static __device__ __forceinline__ float quad_sum(float v){
  int a = __builtin_amdgcn_update_dpp(0, __float_as_int(v), 0xB1, 0xF, 0xF, true); // perm(1,0,3,2)
  v += __int_as_float(a);
  int b = __builtin_amdgcn_update_dpp(0, __float_as_int(v), 0x4E, 0xF, 0xF, true); // perm(2,3,0,1)
  v += __int_as_float(b);
  return v;
}

// ---------------- converted-weight store (device globals) ----------------
constexpr size_t PW_N = (size_t)D * 768;
constexpr size_t IW_N = (size_t)L * TWO_E * D;
constexpr size_t OW_N = (size_t)L * D * E;
constexpr size_t SW_N = (size_t)3 * D * D;
__device__ short g_pw_h[PW_N], g_pw_l[PW_N];
__device__ short g_iw_h[IW_N], g_iw_l[IW_N];
__device__ short g_ow_h[OW_N], g_ow_l[OW_N];
__device__ short g_swx_h[SW_N], g_swx_l[SW_N];

__global__ void convw_kernel(const float* __restrict__ pw, const float* __restrict__ iw,
                             const float* __restrict__ ow, const float* __restrict__ sw){
  size_t i = (size_t)blockIdx.x * 256 + threadIdx.x;
  if (i >= PW_N + IW_N + OW_N + SW_N) return;
  const float* src; short *dh, *dl; size_t j = i;
  if (j < PW_N){ src = pw; dh = g_pw_h; dl = g_pw_l; }
  else if ((j -= PW_N) < IW_N){ src = iw; dh = g_iw_h; dl = g_iw_l; }
  else if ((j -= IW_N) < OW_N){ src = ow; dh = g_ow_h; dl = g_ow_l; }
  else { j -= OW_N; src = sw; dh = g_swx_h; dl = g_swx_l; }
  float f = src[j];
  unsigned short h = f2bf(f);
  dh[j] = (short)h; dl[j] = (short)f2bf(f - bf2f(h));
}

// ---------------- patchify: pixels(f32) -> hi/lo bf16 (M x 768) ----------------
__global__ void patchify_kernel(const float* __restrict__ px,
                                short* __restrict__ oh, short* __restrict__ ol){
  int idx = blockIdx.x * 256 + threadIdx.x;
  if (idx >= M * 768) return;
  int k = idx % 768, m = idx / 768;
  int b = m / Np, n = m % Np;
  int gy = n / G, gx = n % G;
  int c = k / (Pp * Pp), r = k % (Pp * Pp);
  int py = r / Pp, pxi = r % Pp;
  size_t src = ((size_t)(b * 3 + c) * IMG + gy * Pp + py) * IMG + gx * Pp + pxi;
  float f = px[src];
  unsigned short h = f2bf(f);
  oh[idx] = (short)h; ol[idx] = (short)f2bf(f - bf2f(h));
}

// ---------------- layernorm D=384: f32 in -> hi/lo bf16 out ----------------
__global__ __launch_bounds__(256)
void layernorm_bf(const float* __restrict__ x, const float* __restrict__ w,
                  const float* __restrict__ bb, short* __restrict__ oh,
                  short* __restrict__ ol){
  int wave = threadIdx.x >> 6, lane = threadIdx.x & 63;
  int row = blockIdx.x * 4 + wave;
  const float* xr = x + (size_t)row * D;
  float v[6], s = 0.f, sq = 0.f;
  #pragma unroll
  for (int i = 0; i < 6; i++){ v[i] = xr[lane + 64 * i]; s += v[i]; sq += v[i] * v[i]; }
  #pragma unroll
  for (int off = 32; off; off >>= 1){ s += __shfl_xor(s, off); sq += __shfl_xor(sq, off); }
  float mean = s * (1.f / D);
  float var  = sq * (1.f / D) - mean * mean;
  float inv  = 1.0f / sqrtf(var + 1e-5f);
  #pragma unroll
  for (int i = 0; i < 6; i++){
    int c = lane + 64 * i;
    float o = (v[i] - mean) * inv * w[c] + bb[c];
    unsigned short h = f2bf(o);
    oh[(size_t)row * D + c] = (short)h;
    ol[(size_t)row * D + c] = (short)f2bf(o - bf2f(h));
  }
}

// ---------------- final layernorm: f32 -> f32 ----------------
__global__ __launch_bounds__(256)
void layernorm_f32(const float* __restrict__ x, const float* __restrict__ w,
                   const float* __restrict__ bb, float* __restrict__ outf){
  int wave = threadIdx.x >> 6, lane = threadIdx.x & 63;
  int row = blockIdx.x * 4 + wave;
  const float* xr = x + (size_t)row * D;
  float v[6], s = 0.f, sq = 0.f;
  #pragma unroll
  for (int i = 0; i < 6; i++){ v[i] = xr[lane + 64 * i]; s += v[i]; sq += v[i] * v[i]; }
  #pragma unroll
  for (int off = 32; off; off >>= 1){ s += __shfl_xor(s, off); sq += __shfl_xor(sq, off); }
  float mean = s * (1.f / D);
  float var  = sq * (1.f / D) - mean * mean;
  float inv  = 1.0f / sqrtf(var + 1e-5f);
  #pragma unroll
  for (int i = 0; i < 6; i++){
    int c = lane + 64 * i;
    outf[(size_t)row * D + c] = (v[i] - mean) * inv * w[c] + bb[c];
  }
}

// ---------------- in-proj MFMA GEMM, BM=64 x BN=64 (768 blocks = 3/CU even) ----------------
__global__ __launch_bounds__(256)
void gemm_in(const short* __restrict__ Ah, const short* __restrict__ Al,
             size_t woff, const float* __restrict__ bias,
             float* __restrict__ C, float* __restrict__ C2){
  constexpr int BKp = 40;
  __shared__ __align__(16) short sAh[64 * BKp], sAl[64 * BKp];
  __shared__ __align__(16) short sWh[64 * BKp], sWl[64 * BKp];
  const short* Wh = g_iw_h + woff;
  const short* Wl = g_iw_l + woff;
  const int t = threadIdx.x, wid = t >> 6, lane = t & 63;
  const int m0 = blockIdx.y * 64, n0 = blockIdx.x * 64;

  fx4 acc[4];
  #pragma unroll
  for (int a = 0; a < 4; a++)
    #pragma unroll
    for (int i = 0; i < 4; i++) acc[a][i] = 0.f;

  const int r = t >> 2, kp = (t & 3) << 3;
  const int row = lane & 15, kq = lane >> 4;

  for (int kt = 0; kt < D; kt += 32){
    *(bf16x8*)&sAh[r * BKp + kp] = *(const bf16x8*)(Ah + (size_t)(m0 + r) * D + kt + kp);
    *(bf16x8*)&sAl[r * BKp + kp] = *(const bf16x8*)(Al + (size_t)(m0 + r) * D + kt + kp);
    *(bf16x8*)&sWh[r * BKp + kp] = *(const bf16x8*)(Wh + (size_t)(n0 + r) * D + kt + kp);
    *(bf16x8*)&sWl[r * BKp + kp] = *(const bf16x8*)(Wl + (size_t)(n0 + r) * D + kt + kp);
    __syncthreads();
    bf16x8 bh = *(const bf16x8*)&sWh[(wid * 16 + row) * BKp + kq * 8];
    bf16x8 bl = *(const bf16x8*)&sWl[(wid * 16 + row) * BKp + kq * 8];
    #pragma unroll
    for (int tm = 0; tm < 4; tm++){
      bf16x8 ah = *(const bf16x8*)&sAh[(tm * 16 + row) * BKp + kq * 8];
      bf16x8 al = *(const bf16x8*)&sAl[(tm * 16 + row) * BKp + kq * 8];
      acc[tm] = __builtin_amdgcn_mfma_f32_16x16x32_bf16(ah, bh, acc[tm], 0, 0, 0);
      acc[tm] = __builtin_amdgcn_mfma_f32_16x16x32_bf16(ah, bl, acc[tm], 0, 0, 0);
      acc[tm] = __builtin_amdgcn_mfma_f32_16x16x32_bf16(al, bh, acc[tm], 0, 0, 0);
    }
    __syncthreads();
  }

  const int row4 = (lane >> 4) * 4, coln = lane & 15;
  #pragma unroll
  for (int tm = 0; tm < 4; tm++){
    int n = n0 + wid * 16 + coln;
    int mb = m0 + tm * 16 + row4;
    float4 v4;
    float* vp = (float*)&v4;
    #pragma unroll
    for (int i = 0; i < 4; i++) vp[i] = acc[tm][i] + bias[n];
    if (n < E){
      *(float4*)&C[(size_t)n * M + mb] = v4;          // xmT transposed
    } else {
      #pragma unroll
      for (int i = 0; i < 4; i++){
        float sig = 1.f / (1.f + expf(-vp[i]));
        vp[i] = vp[i] * sig;
      }
      *(float4*)&C2[(size_t)(n - E) * M + mb] = v4;   // zst transposed
    }
  }
}

// ---------------- patch MFMA GEMM 64x64 (pre-split A, +pos epilogue) ----------------
__global__ __launch_bounds__(256)
void gemm_patch(const short* __restrict__ Ah, const short* __restrict__ Al,
                const float* __restrict__ bias, float* __restrict__ C,
                const float* __restrict__ pos){
  constexpr int BKp = 40;
  __shared__ __align__(16) short sAh[64 * BKp], sAl[64 * BKp];
  __shared__ __align__(16) short sWh[64 * BKp], sWl[64 * BKp];
  const int t = threadIdx.x, wid = t >> 6, lane = t & 63;
  const int m0 = blockIdx.y * 64, n0 = blockIdx.x * 64;

  fx4 acc[4];
  #pragma unroll
  for (int a = 0; a < 4; a++)
    #pragma unroll
    for (int i = 0; i < 4; i++) acc[a][i] = 0.f;

  const int r = t >> 2, kp = (t & 3) << 3;
  const int row = lane & 15, kq = lane >> 4;

  for (int kt = 0; kt < 768; kt += 32){
    *(bf16x8*)&sAh[r * BKp + kp] = *(const bf16x8*)(Ah + (size_t)(m0 + r) * 768 + kt + kp);
    *(bf16x8*)&sAl[r * BKp + kp] = *(const bf16x8*)(Al + (size_t)(m0 + r) * 768 + kt + kp);
    *(bf16x8*)&sWh[r * BKp + kp] = *(const bf16x8*)(g_pw_h + (size_t)(n0 + r) * 768 + kt + kp);
    *(bf16x8*)&sWl[r * BKp + kp] = *(const bf16x8*)(g_pw_l + (size_t)(n0 + r) * 768 + kt + kp);
    __syncthreads();
    bf16x8 bh = *(const bf16x8*)&sWh[(wid * 16 + row) * BKp + kq * 8];
    bf16x8 bl = *(const bf16x8*)&sWl[(wid * 16 + row) * BKp + kq * 8];
    #pragma unroll
    for (int tm = 0; tm < 4; tm++){
      bf16x8 ah = *(const bf16x8*)&sAh[(tm * 16 + row) * BKp + kq * 8];
      bf16x8 al = *(const bf16x8*)&sAl[(tm * 16 + row) * BKp + kq * 8];
      acc[tm] = __builtin_amdgcn_mfma_f32_16x16x32_bf16(ah, bh, acc[tm], 0, 0, 0);
      acc[tm] = __builtin_amdgcn_mfma_f32_16x16x32_bf16(ah, bl, acc[tm], 0, 0, 0);
      acc[tm] = __builtin_amdgcn_mfma_f32_16x16x32_bf16(al, bh, acc[tm], 0, 0, 0);
    }
    __syncthreads();
  }

  const int row4 = (lane >> 4) * 4, coln = lane & 15;
  #pragma unroll
  for (int tm = 0; tm < 4; tm++){
    int n = n0 + wid * 16 + coln;
    int mb = m0 + tm * 16 + row4;
    #pragma unroll
    for (int i = 0; i < 4; i++){
      int m = mb + i;
      C[(size_t)m * D + n] = acc[tm][i] + bias[n] + pos[(size_t)(m & (Np - 1)) * D + n];
    }
  }
}

// ---------------- scale MFMA GEMM 64x64: A = f32 x, hi/lo converted in staging ----------------
__global__ __launch_bounds__(256)
void gemm_scale(const float* __restrict__ A, size_t woff,
                const float* __restrict__ bias, float* __restrict__ C){
  constexpr int BKp = 40;
  __shared__ __align__(16) short sAh[64 * BKp], sAl[64 * BKp];
  __shared__ __align__(16) short sWh[64 * BKp], sWl[64 * BKp];
  const short* Wh = g_swx_h + woff;
  const short* Wl = g_swx_l + woff;
  const int t = threadIdx.x, wid = t >> 6, lane = t & 63;
  const int m0 = blockIdx.y * 64, n0 = blockIdx.x * 64;

  fx4 acc[4];
  #pragma unroll
  for (int a = 0; a < 4; a++)
    #pragma unroll
    for (int i = 0; i < 4; i++) acc[a][i] = 0.f;

  const int r = t >> 2, kp = (t & 3) << 3;
  const int row = lane & 15, kq = lane >> 4;

  for (int kt = 0; kt < D; kt += 32){
    {
      const float* ap = A + (size_t)(m0 + r) * D + kt + kp;
      float4 f0 = *(const float4*)ap, f1 = *(const float4*)(ap + 4);
      float f[8] = {f0.x, f0.y, f0.z, f0.w, f1.x, f1.y, f1.z, f1.w};
      short hh[8], ll[8];
      #pragma unroll
      for (int i = 0; i < 8; i++){
        unsigned short h = f2bf(f[i]);
        hh[i] = (short)h; ll[i] = (short)f2bf(f[i] - bf2f(h));
      }
      *(bf16x8*)&sAh[r * BKp + kp] = *(bf16x8*)hh;
      *(bf16x8*)&sAl[r * BKp + kp] = *(bf16x8*)ll;
    }
    *(bf16x8*)&sWh[r * BKp + kp] = *(const bf16x8*)(Wh + (size_t)(n0 + r) * D + kt + kp);
    *(bf16x8*)&sWl[r * BKp + kp] = *(const bf16x8*)(Wl + (size_t)(n0 + r) * D + kt + kp);
    __syncthreads();
    bf16x8 bh = *(const bf16x8*)&sWh[(wid * 16 + row) * BKp + kq * 8];
    bf16x8 bl = *(const bf16x8*)&sWl[(wid * 16 + row) * BKp + kq * 8];
    #pragma unroll
    for (int tm = 0; tm < 4; tm++){
      bf16x8 ah = *(const bf16x8*)&sAh[(tm * 16 + row) * BKp + kq * 8];
      bf16x8 al = *(const bf16x8*)&sAl[(tm * 16 + row) * BKp + kq * 8];
      acc[tm] = __builtin_amdgcn_mfma_f32_16x16x32_bf16(ah, bh, acc[tm], 0, 0, 0);
      acc[tm] = __builtin_amdgcn_mfma_f32_16x16x32_bf16(ah, bl, acc[tm], 0, 0, 0);
      acc[tm] = __builtin_amdgcn_mfma_f32_16x16x32_bf16(al, bh, acc[tm], 0, 0, 0);
    }
    __syncthreads();
  }

  const int row4 = (lane >> 4) * 4, coln = lane & 15;
  #pragma unroll
  for (int tm = 0; tm < 4; tm++){
    int n = n0 + wid * 16 + coln;
    int mb = m0 + tm * 16 + row4;
    #pragma unroll
    for (int i = 0; i < 4; i++){
      int m = mb + i;
      C[(size_t)m * D + n] = acc[tm][i] + bias[n];
    }
  }
}

// ---------------- out-proj MFMA GEMM, TRANSPOSED A, SPLIT-K x4 (768 blocks = 3/CU) ----------------
// R10: was 192 blocks = 0.75/CU -> duration = full 24-k-iter chain with 25% of CUs idle.
// Split K=768 into 4 slices of 192; each block atomically accumulates its partial into C.
// C already holds the residual, so atomicAdd(partial + [kz==0]bias) reproduces
// residual + bias + GEMM exactly up to f32 summation order. xBC zeroing gated to kz==0.
__global__ __launch_bounds__(256)
void gemm_bf_at(const short* __restrict__ ATh, const short* __restrict__ ATl, int K,
                size_t woff, const float* __restrict__ bias,
                float* __restrict__ C, int ncols, float* __restrict__ zbuf){
  constexpr int BKp = 40;
  __shared__ __align__(16) short sAh[64 * BKp], sAl[64 * BKp];
  __shared__ __align__(16) short sWh[64 * BKp], sWl[64 * BKp];
  const short* Wh = g_ow_h + woff;
  const short* Wl = g_ow_l + woff;
  const int t = threadIdx.x, wid = t >> 6, lane = t & 63;
  const int m0 = blockIdx.y * 64, n0 = blockIdx.x * 64;
  const int kz = blockIdx.z;
  const int kslice = K >> 2;                 // 192
  const int k0 = kz * kslice;

  fx4 acc[4];
  #pragma unroll
  for (int a = 0; a < 4; a++)
    #pragma unroll
    for (int i = 0; i < 4; i++) acc[a][i] = 0.f;

  const int rw = t >> 2, kpw = (t & 3) << 3;
  const int kr2 = (t & 15) * 2, mc4 = (t >> 4) * 4;
  const int row = lane & 15, kq = lane >> 4;

  for (int kt = k0; kt < k0 + kslice; kt += 32){
    {
      const uint2 h0 = *(const uint2*)(ATh + (size_t)(kt + kr2) * M + m0 + mc4);
      const uint2 h1 = *(const uint2*)(ATh + (size_t)(kt + kr2 + 1) * M + m0 + mc4);
      const uint2 l0 = *(const uint2*)(ATl + (size_t)(kt + kr2) * M + m0 + mc4);
      const uint2 l1 = *(const uint2*)(ATl + (size_t)(kt + kr2 + 1) * M + m0 + mc4);
      const unsigned int h0a[2] = {h0.x, h0.y}, h1a[2] = {h1.x, h1.y};
      const unsigned int l0a[2] = {l0.x, l0.y}, l1a[2] = {l1.x, l1.y};
      #pragma unroll
      for (int j = 0; j < 4; j++){
        unsigned int s0 = (h0a[j >> 1] >> ((j & 1) * 16)) & 0xFFFFu;
        unsigned int s1 = (h1a[j >> 1] >> ((j & 1) * 16)) & 0xFFFFu;
        *(unsigned int*)&sAh[(mc4 + j) * BKp + kr2] = s0 | (s1 << 16);
        unsigned int t0 = (l0a[j >> 1] >> ((j & 1) * 16)) & 0xFFFFu;
        unsigned int t1 = (l1a[j >> 1] >> ((j & 1) * 16)) & 0xFFFFu;
        *(unsigned int*)&sAl[(mc4 + j) * BKp + kr2] = t0 | (t1 << 16);
      }
    }
    *(bf16x8*)&sWh[rw * BKp + kpw] = *(const bf16x8*)(Wh + (size_t)(n0 + rw) * K + kt + kpw);
    *(bf16x8*)&sWl[rw * BKp + kpw] = *(const bf16x8*)(Wl + (size_t)(n0 + rw) * K + kt + kpw);
    __syncthreads();
    bf16x8 bh = *(const bf16x8*)&sWh[(wid * 16 + row) * BKp + kq * 8];
    bf16x8 bl = *(const bf16x8*)&sWl[(wid * 16 + row) * BKp + kq * 8];
    #pragma unroll
    for (int tm = 0; tm < 4; tm++){
      bf16x8 ah = *(const bf16x8*)&sAh[(tm * 16 + row) * BKp + kq * 8];
      bf16x8 al = *(const bf16x8*)&sAl[(tm * 16 + row) * BKp + kq * 8];
      acc[tm] = __builtin_amdgcn_mfma_f32_16x16x32_bf16(ah, bh, acc[tm], 0, 0, 0);
      acc[tm] = __builtin_amdgcn_mfma_f32_16x16x32_bf16(ah, bl, acc[tm], 0, 0, 0);
      acc[tm] = __builtin_amdgcn_mfma_f32_16x16x32_bf16(al, bh, acc[tm], 0, 0, 0);
    }
    __syncthreads();
  }

  const int row4 = (lane >> 4) * 4, coln = lane & 15;
  #pragma unroll
  for (int tm = 0; tm < 4; tm++)
    #pragma unroll
    for (int i = 0; i < 4; i++){
      int m = m0 + tm * 16 + row4 + i;
      int n = n0 + wid * 16 + coln;
      float v = acc[tm][i] + ((kz == 0) ? bias[n] : 0.f);
      atomicAdd(&C[(size_t)m * ncols + n], v);
    }

  // zero xBC for next layer's xp accumulation (stream order guarantees visibility)
  if (kz == 0){
    int gid = blockIdx.y * gridDim.x + blockIdx.x;
    int idx = gid * 256 + t;
    if (idx < M * 16)
      *(float2*)&zbuf[idx * 2] = make_float2(0.f, 0.f);
  }
}

// ---------------- xp GEMM with FUSED depthwise conv+SiLU in A-staging ----------------
// K-split 8 (96 channels/block) -> 256 blocks = 1/CU even. Staging thread owns channel
// e=kt+ty and 4 consecutive m; computes causal conv+SiLU in regs, writes both LDS As
// (GEMM input) and xcT (for scan). Each (e,m) covered exactly once.
// NOTE (R7 lesson): fusions only free when fused grid covers each element ONCE.
__global__ __launch_bounds__(256)
void gemm_xp(const float* __restrict__ xmT, const float* __restrict__ cw,
             const float* __restrict__ cb, const float* __restrict__ W,
             const float* __restrict__ bias, float* __restrict__ xcT,
             float* __restrict__ C){
  __shared__ float As[16][68];
  __shared__ float Ws[16][32 + 1];
  int tid = threadIdx.x;
  int tx = tid & 15, ty = tid >> 4;
  int m0 = blockIdx.y * 64, kb = blockIdx.x * 96;
  float acc[4][2];
  #pragma unroll
  for (int i = 0; i < 4; i++){ acc[i][0] = 0.f; acc[i][1] = 0.f; }
  for (int kt = kb; kt < kb + 96; kt += 16){
    { // fused conv staging: channel e = kt+ty, cols m = m0 + tx*4 + j
      int e = kt + ty;
      int mbase = m0 + tx * 4;
      const float* src = xmT + (size_t)e * M + mbase;
      float4 cur = *(const float4*)src;
      float4 prv = make_float4(0.f, 0.f, 0.f, 0.f);
      if (mbase >= 4) prv = *(const float4*)(src - 4);
      float4 w4 = *(const float4*)(cw + e * 4);
      float cb_e = cb[e];
      float vin[8] = {prv.x, prv.y, prv.z, prv.w, cur.x, cur.y, cur.z, cur.w};
      float4 outv;
      float* op = (float*)&outv;
      #pragma unroll
      for (int j = 0; j < 4; j++){
        int m = mbase + j, n = m & (Np - 1);
        float a = cb_e + w4.w * vin[4 + j];
        if (n >= 1) a += w4.z * vin[3 + j];
        if (n >= 2) a += w4.y * vin[2 + j];
        if (n >= 3) a += w4.x * vin[1 + j];
        float sig = 1.f / (1.f + expf(-a));
        op[j] = a * sig;
      }
      *(float4*)&As[ty][tx * 4] = outv;
      *(float4*)&xcT[(size_t)e * M + mbase] = outv;
    }
    if (tid < 128){
      int c = tid >> 2, kk = (tid & 3) << 2;
      const float* wp = W + (size_t)c * E + kt + kk;
      Ws[kk + 0][c] = wp[0]; Ws[kk + 1][c] = wp[1];
      Ws[kk + 2][c] = wp[2]; Ws[kk + 3][c] = wp[3];
    }
    __syncthreads();
    #pragma unroll
    for (int k = 0; k < 16; k++){
      float a[4], w[2];
      #pragma unroll
      for (int i = 0; i < 4; i++) a[i] = As[k][ty * 4 + i];
      w[0] = Ws[k][tx * 2]; w[1] = Ws[k][tx * 2 + 1];
      #pragma unroll
      for (int i = 0; i < 4; i++){ acc[i][0] += a[i] * w[0]; acc[i][1] += a[i] * w[1]; }
    }
    __syncthreads();
  }
  #pragma unroll
  for (int i = 0; i < 4; i++){
    int m = m0 + ty * 4 + i;
    #pragma unroll
    for (int j = 0; j < 2; j++){
      int n = tx * 2 + j;
      float v = acc[i][j];
      if (blockIdx.x == 0) v += bias[n];
      atomicAdd(&C[(size_t)m * 32 + n], v);
    }
  }
}

// ---------------- quad-per-chunk selective scan, register-prefetch pipelined (R3-best) ----------------
// 64 chunks of 16 positions; each chunk owned by a 4-lane quad, each lane holds 4 s-values
// in registers. Phase A: chunk-local h + sum(dt), 8-deep xb register FIFO. Phase B: 64-step
// serial combine on 16 lanes (LDS-based: keeps VGPR ~20-32; register-monoid variants in
// R4/R5 pushed VGPR >64 and lost 2x occupancy — do not revisit). Phase C: exact chain
// seeded with Hin, 6-deep dual-stream FIFO, 4-FMA dot + quad DPP reduce.
// dt in [1e-4,1], A in [-16,-1] => dt*a in [-16,-1e-4]; ref's [-20,0] clip can't fire.
// softplus: log2/exp2 hw ops; overflow->inf->clamp(1.0) and underflow->0->clamp(1e-4) exact.
__global__ __launch_bounds__(256)
void scan_kernel(const float* __restrict__ xcT, const float* __restrict__ zst,
                 const float* __restrict__ xBC,
                 const float* __restrict__ Aptr, const float* __restrict__ Dp,
                 const float* __restrict__ dt_w, const float* __restrict__ dt_b,
                 short* __restrict__ yh, short* __restrict__ yl){
  __shared__ float sdx[2176];       // {dt,xcv} pairs, swizzled: word = 2*pos + 2*(pos>>4)
  __shared__ float sHin[64 * 16];   // Hin[c][s]
  __shared__ float scr[2048];       // phase A/B: hloc[0..1023] + prodA[1024..2047]; phase C alias: yloc
  const int t = threadIdx.x;
  const int c = t >> 2;             // chunk 0..63
  const int u = t & 3;              // lane-in-quad
  const int r = blockIdx.x, b = r / E, e = r % E;
  const int bNp = b * Np;
  const float dpe = Dp[e];
  constexpr float LOG2E  = 1.4426950408889634f;
  constexpr float RLOG2E = 0.6931471805599453f;
  float4 a4 = *(const float4*)(Aptr + e * S + u * 4);
  const float a20 = a4.x * LOG2E, a21 = a4.y * LOG2E, a22 = a4.z * LOG2E, a23 = a4.w * LOG2E;
  const float* xcp = xcT + (size_t)e * M + bNp;
  const float* zsp = zst + (size_t)e * M + bNp;

  { // preload: dt[pos] = clip(softplus(xB . dt_w[e] + dt_b[e])), stage {dt,xc} swizzled.
    // all 4 xcp loads upfront; xBC row loads double-buffered 2-deep; hw-transcendental softplus.
    const float* dw = dt_w + e * 16;
    float4 w0 = *(const float4*)dw,       w1 = *(const float4*)(dw + 4);
    float4 w2 = *(const float4*)(dw + 8), w3 = *(const float4*)(dw + 12);
    float db = dt_b[e];
    float xcl[4];
    #pragma unroll
    for (int p = 0; p < 4; p++) xcl[p] = xcp[t + p * 256];
    float4 ra[2][4];
    {
      const float* xb0 = xBC + (size_t)(bNp + t) * 32;
      #pragma unroll
      for (int j = 0; j < 4; j++) ra[0][j] = *(const float4*)(xb0 + j * 4);
    }
    #pragma unroll
    for (int p = 0; p < 4; p++){
      int q = t + p * 256;
      float4 a0 = ra[p & 1][0], a1 = ra[p & 1][1], a2 = ra[p & 1][2], a3 = ra[p & 1][3];
      if (p < 3){
        const float* xbn = xBC + (size_t)(bNp + q + 256) * 32;
        #pragma unroll
        for (int j = 0; j < 4; j++) ra[(p + 1) & 1][j] = *(const float4*)(xbn + j * 4);
      }
      float v = db + a0.x * w0.x + a0.y * w0.y + a0.z * w0.z + a0.w * w0.w
                   + a1.x * w1.x + a1.y * w1.y + a1.z * w1.z + a1.w * w1.w
                   + a2.x * w2.x + a2.y * w2.y + a2.z * w2.z + a2.w * w2.w
                   + a3.x * w3.x + a3.y * w3.y + a3.z * w3.z + a3.w * w3.w;
      v = flog2(1.f + fexp2(v * LOG2E)) * RLOG2E;         // softplus
      v = fminf(fmaxf(v, 1e-4f), 1.0f);
      int w = (q << 1) + ((q >> 4) << 1);
      *(float2*)&sdx[w] = make_float2(v, xcl[p]);
    }
  }
  __syncthreads();

  const int pos0 = c * 16;
  const int wbase = 34 * c;                              // sdx word base for this chunk
  const float* xbp  = xBC + ((size_t)(bNp + pos0) * 32 + u * 4);
  const float* xcsp = xbp + 16;

  // ---- phase A: chunk-local h (from 0) + running dt-sum, 8-deep xb FIFO ----
  float h0 = 0.f, h1 = 0.f, h2 = 0.f, h3 = 0.f, sdt = 0.f;
  {
    float4 xbv[8];
    #pragma unroll
    for (int j = 0; j < 8; j++) xbv[j] = *(const float4*)(xbp + (size_t)j * 32);
    #pragma unroll
    for (int i = 0; i < 16; i++){
      float2 dx = *(const float2*)&sdx[wbase + 2 * i];
      float4 xb = xbv[i & 7];
      if (i < 8) xbv[i] = *(const float4*)(xbp + (size_t)(i + 8) * 32);
      float dt = dx.x, xcv = dx.y;
      sdt += dt;
      float e0 = fexp2(dt * a20), e1 = fexp2(dt * a21);
      float e2 = fexp2(dt * a22), e3 = fexp2(dt * a23);
      h0 = e0 * h0 + xb.x * xcv;
      h1 = e1 * h1 + xb.y * xcv;
      h2 = e2 * h2 + xb.z * xcv;
      h3 = e3 * h3 + xb.w * xcv;
    }
  }
  // chunk decay = exp(sum(dt)*a) ; store h, decay
  {
    float p0 = fexp2(sdt * a20), p1 = fexp2(sdt * a21);
    float p2 = fexp2(sdt * a22), p3 = fexp2(sdt * a23);
    *(float4*)&scr[c * 16 + u * 4]        = make_float4(h0, h1, h2, h3);
    *(float4*)&scr[1024 + c * 16 + u * 4] = make_float4(p0, p1, p2, p3);
  }
  __syncthreads();

  // ---- phase B: serial 64-chunk combine on 16 lanes (s = t) ----
  if (t < 16){
    float H = 0.f;
    #pragma unroll 8
    for (int cc = 0; cc < 64; cc++){
      sHin[cc * 16 + t] = H;
      H = scr[1024 + cc * 16 + t] * H + scr[cc * 16 + t];
    }
  }
  __syncthreads();

  // epilogue z load hoisted: hides HBM latency under phase C
  float4 z4 = *(const float4*)&zsp[t * 4];

  // ---- phase C: exact chain seeded with Hin; 6-deep dual-stream FIFO ----
  {
    float4 hin = *(const float4*)&sHin[c * 16 + u * 4];
    h0 = hin.x; h1 = hin.y; h2 = hin.z; h3 = hin.w;
  }
  float* yloc = scr;                 // alias (hloc/prodA dead after phase B)
  const int ybase = pos0 + ((pos0 >> 4) << 2);
  {
    float4 xbv[6], xcs6[6];
    #pragma unroll
    for (int j = 0; j < 6; j++){
      xbv[j]  = *(const float4*)(xbp  + (size_t)j * 32);
      xcs6[j] = *(const float4*)(xcsp + (size_t)j * 32);
    }
    #pragma unroll
    for (int i = 0; i < 16; i++){
      float2 dx = *(const float2*)&sdx[wbase + 2 * i];
      float4 xb  = xbv[i % 6];
      float4 xcs = xcs6[i % 6];
      if (i < 10){
        xbv[i % 6]  = *(const float4*)(xbp  + (size_t)(i + 6) * 32);
        xcs6[i % 6] = *(const float4*)(xcsp + (size_t)(i + 6) * 32);
      }
      float dt = dx.x, xcv = dx.y;
      float e0 = fexp2(dt * a20), e1 = fexp2(dt * a21);
      float e2 = fexp2(dt * a22), e3 = fexp2(dt * a23);
      h0 = e0 * h0 + xb.x * xcv;
      h1 = e1 * h1 + xb.y * xcv;
      h2 = e2 * h2 + xb.z * xcv;
      h3 = e3 * h3 + xb.w * xcv;
      float yp = h0 * xcs.x + h1 * xcs.y + h2 * xcs.z + h3 * xcs.w;
      yp = quad_sum(yp);
      if (u == 0) yloc[ybase + i] = yp;
    }
  }
  __syncthreads();

  { // epilogue: y = (scan + Dp*xc) * silu(z), packed hi/lo bf16, [e][m] layout
    int n4 = t * 4;
    const float* zp = (const float*)&z4;
    int yb = n4 + ((n4 >> 4) << 2);
    int xw = (n4 << 1) + ((n4 >> 4) << 1);
    unsigned int hpack[2], lpack[2];
    #pragma unroll
    for (int half = 0; half < 2; half++){
      unsigned int hp = 0, lp = 0;
      #pragma unroll
      for (int j = 0; j < 2; j++){
        int jj = half * 2 + j;
        float xcv = sdx[xw + 2 * jj + 1];
        float val = (yloc[yb + jj] + dpe * xcv) * zp[jj];
        unsigned short hh = f2bf(val);
        unsigned short ll = f2bf(val - bf2f(hh));
        hp |= ((unsigned int)hh) << (16 * j);
        lp |= ((unsigned int)ll) << (16 * j);
      }
      hpack[half] = hp; lpack[half] = lp;
    }
    size_t o = (size_t)e * M + bNp + n4;
    *(uint2*)&yh[o] = make_uint2(hpack[0], hpack[1]);
    *(uint2*)&yl[o] = make_uint2(lpack[0], lpack[1]);
  }
}

extern "C" void kernel_launch(void* const* d_in, const int* in_sizes, int n_in,
                              void* d_out, int out_size, void* d_ws, size_t ws_size,
                              hipStream_t stream){
  const float* px      = (const float*)d_in[0];
  const float* patch_w = (const float*)d_in[1];
  const float* patch_b = (const float*)d_in[2];
  const float* pos     = (const float*)d_in[3];
  const float* norm_w  = (const float*)d_in[4];
  const float* norm_b  = (const float*)d_in[5];
  const float* in_w    = (const float*)d_in[6];
  const float* in_b    = (const float*)d_in[7];
  const float* conv_w  = (const float*)d_in[8];
  const float* conv_b  = (const float*)d_in[9];
  const float* xp_w    = (const float*)d_in[10];
  const float* xp_b    = (const float*)d_in[11];
  const float* dt_w    = (const float*)d_in[12];
  const float* dt_b    = (const float*)d_in[13];
  const float* Aab     = (const float*)d_in[14];
  const float* Dp      = (const float*)d_in[15];
  const float* out_w   = (const float*)d_in[16];
  const float* out_b   = (const float*)d_in[17];
  const float* fnorm_w = (const float*)d_in[18];
  const float* fnorm_b = (const float*)d_in[19];
  const float* scale_w = (const float*)d_in[20];
  const float* scale_b = (const float*)d_in[21];
  float* out = (float*)d_out;

  // workspace
  float* x   = (float*)d_ws;                  // M*D
  float* xmT = x + (size_t)M * D;             // E*M f32 (transposed x_main)
  float* zst = xmT + (size_t)M * E;           // E*M
  float* xcT = zst + (size_t)M * E;           // E*M
  float* xBC = xcT + (size_t)M * E;           // M*32 ([xB|xC] halves)
  short* xnh = (short*)(xBC + (size_t)M * 32);// M*D
  short* xnl = xnh + (size_t)M * D;           // M*D
  short* yh  = (short*)xmT;                   // E*M shorts (alias: dead x_main)
  short* yl  = yh + (size_t)M * E;
  short* pbh = yh, *pbl = yl;                 // patch buffer alias

  constexpr size_t TOTW = PW_N + IW_N + OW_N + SW_N;
  convw_kernel<<<(int)((TOTW + 255) / 256), 256, 0, stream>>>(patch_w, in_w, out_w, scale_w);
  hipMemsetAsync(xBC, 0, (size_t)M * 32 * sizeof(float), stream);   // layer-0 init

  patchify_kernel<<<(M * 768 + 255) / 256, 256, 0, stream>>>(px, pbh, pbl);
  gemm_patch<<<dim3(D / 64, M / 64), 256, 0, stream>>>(pbh, pbl, patch_b, x, pos);

  for (int l = 0; l < L; l++){
    layernorm_bf<<<M / 4, 256, 0, stream>>>(x, norm_w + l * D, norm_b + l * D, xnh, xnl);
    gemm_in<<<dim3(TWO_E / 64, M / 64), 256, 0, stream>>>(
        xnh, xnl, (size_t)l * TWO_E * D, in_b + l * TWO_E, xmT, zst);
    gemm_xp<<<dim3(8, M / 64), 256, 0, stream>>>(
        xmT, conv_w + (size_t)l * E * 4, conv_b + l * E,
        xp_w + (size_t)l * 32 * E, xp_b + l * 32, xcT, xBC);
    scan_kernel<<<Bz * E, 256, 0, stream>>>(
        xcT, zst, xBC, Aab + (size_t)l * E * S, Dp + l * E,
        dt_w + (size_t)l * E * S, dt_b + l * E, yh, yl);
    gemm_bf_at<<<dim3(D / 64, M / 64, 4), 256, 0, stream>>>(
        yh, yl, E, (size_t)l * D * E, out_b + l * D, x, D, xBC);
    if (l % 4 == 0 && l / 4 < 3){
      int j = l / 4;
      gemm_scale<<<dim3(D / 64, M / 64), 256, 0, stream>>>(
          x, (size_t)j * D * D, scale_b + j * D, out + (size_t)(1 + j) * M * D);
    }
  }
  layernorm_f32<<<M / 4, 256, 0, stream>>>(x, fnorm_w, fnorm_b, out);
}